// Round 9
// baseline (1894.902 us; speedup 1.0000x reference)
//
#include <hip/hip_runtime.h>
#include <hip/hip_bf16.h>
#include <stdint.h>

typedef unsigned int u32;
typedef unsigned short u16;
typedef __attribute__((ext_vector_type(8))) short bf16x8;
typedef __attribute__((ext_vector_type(4))) float f32x4;

#define NPTS 524288
#define FF 4
#define HH 64
#define WW 512
#define SS 262144
#define EPSV 1e-5f
#define NB 8192      // 64 points per block (fallback mega4)
#define RCAP 80
#define VCAP 80

__device__ __forceinline__ float bf2f(u16 h){ return __uint_as_float(((u32)h)<<16); }
__device__ __forceinline__ u16 f2bf(float f){
  u32 u = __float_as_uint(f);
  return (u16)((u + 0x7FFFu + ((u>>16)&1u)) >> 16);   // RNE (monotone)
}

__device__ __forceinline__ void point_feats(int p, const float* __restrict__ pts,
    const u32* __restrict__ lin, const u32* __restrict__ counts,
    const float* __restrict__ vsum, float f[8], u32* vout){
  float4 pt = ((const float4*)pts)[p];
  u32 v = lin[p];
  float cnt = fmaxf((float)counts[v], 1.0f);
  float inv = 1.0f/cnt;
  float mx = vsum[v*3+0]*inv, my = vsum[v*3+1]*inv, mz = vsum[v*3+2]*inv;
  float dist = sqrtf(pt.x*pt.x + pt.y*pt.y + pt.z*pt.z);
  f[0]=pt.x; f[1]=pt.y; f[2]=pt.z; f[3]=pt.w; f[4]=dist;
  f[5]=pt.x-mx; f[6]=pt.y-my; f[7]=pt.z-mz;
  *vout = v;
}

// ---------------- pass 1: linear voxel id + counts + coord sums ----------------
__global__ __launch_bounds__(256) void k_lin(const float* __restrict__ pts,
                                             const int* __restrict__ coors,
                                             u32* __restrict__ lin,
                                             u32* __restrict__ counts,
                                             float* __restrict__ vsum){
  int p = blockIdx.x*256 + threadIdx.x;
  int4 c = ((const int4*)coors)[p];
  u32 v = ((u32)((c.x*FF + c.y)*HH + c.z))*WW + (u32)c.w;
  lin[p] = v;
  atomicAdd(&counts[v], 1u);
  float4 pt = ((const float4*)pts)[p];
  atomicAdd(&vsum[v*3+0], pt.x);
  atomicAdd(&vsum[v*3+1], pt.y);
  atomicAdd(&vsum[v*3+2], pt.z);
}

// ---------------- counting-sort scan ----------------
__global__ __launch_bounds__(256) void k_scan_a(const u32* __restrict__ counts,
                                                u32* __restrict__ blockSums){
  __shared__ u32 lds[256];
  int b = blockIdx.x, t = threadIdx.x;
  uint4 c4 = ((const uint4*)counts)[b*256 + t];
  lds[t] = c4.x + c4.y + c4.z + c4.w;
  __syncthreads();
  for(int s=128; s>0; s>>=1){ if(t<s) lds[t] += lds[t+s]; __syncthreads(); }
  if(t==0) blockSums[b] = lds[0];
}

__global__ void k_scan_b(u32* blockSums){
  if(threadIdx.x==0){
    u32 run = 0;
    for(int i=0;i<256;i++){ u32 v = blockSums[i]; blockSums[i] = run; run += v; }
  }
}

__global__ __launch_bounds__(256) void k_scan_c(const u32* __restrict__ counts,
                                                const u32* __restrict__ blockSums,
                                                u32* __restrict__ offsets,
                                                u32* __restrict__ cursor){
  __shared__ u32 lds[256];
  int b = blockIdx.x, t = threadIdx.x;
  uint4 c4 = ((const uint4*)counts)[b*256 + t];
  u32 mysum = c4.x + c4.y + c4.z + c4.w;
  lds[t] = mysum;
  __syncthreads();
  for(int d=1; d<256; d<<=1){
    u32 v = (t>=d) ? lds[t-d] : 0u;
    __syncthreads();
    lds[t] += v;
    __syncthreads();
  }
  u32 off = blockSums[b] + (t>0 ? lds[t-1] : 0u);
  u32 base = (u32)(b*1024 + t*4);
  offsets[base+0]=off; cursor[base+0]=off; off += c4.x;
  offsets[base+1]=off; cursor[base+1]=off; off += c4.y;
  offsets[base+2]=off; cursor[base+2]=off; off += c4.z;
  offsets[base+3]=off; cursor[base+3]=off; off += c4.w;
  if(base+4 == SS) offsets[SS] = off;
}

__global__ __launch_bounds__(256) void k_scatter(const u32* __restrict__ lin,
                                                 u32* __restrict__ cursor,
                                                 u32* __restrict__ order){
  int p = blockIdx.x*256 + threadIdx.x;
  u32 v = lin[p];
  u32 pos = atomicAdd(&cursor[v], 1u);
  order[pos] = p;
}

// ---------------- weight prep: bf16 transposed ----------------
__global__ __launch_bounds__(256) void k_prep(const float* __restrict__ W2,
    const float* __restrict__ W3, const float* __restrict__ W4,
    const float* __restrict__ Wc,
    u16* __restrict__ W2t, u16* __restrict__ W3t, u16* __restrict__ W4t,
    u16* __restrict__ Wct){
  int i = blockIdx.x*256 + threadIdx.x;
  if(i < 8192){
    int k = i >> 7, n = i & 127;
    W2t[n*64 + k] = f2bf(W2[i]);
  } else if(i < 8192+32768){
    int j = i - 8192;
    int k = j >> 8, n = j & 255;
    W3t[n*128 + k] = f2bf(W3[j]);
  } else if(i < 8192+32768+65536){
    int j = i - (8192+32768);
    int k = j >> 8, n = j & 255;
    W4t[n*256 + k] = f2bf(W4[j]);
  } else if(i < 8192+32768+65536+16384){
    int j = i - (8192+32768+65536);
    int k = j >> 6, n = j & 63;
    Wct[n*256 + k] = f2bf(Wc[j]);
  }
}

// ---------------- stats0 (proven) ----------------
__global__ __launch_bounds__(256) void k_stats0(const float* __restrict__ pts,
    const u32* __restrict__ lin, const u32* __restrict__ counts,
    const float* __restrict__ vsum, float* __restrict__ sum0, float* __restrict__ sq0){
  int p = blockIdx.x*256 + threadIdx.x;
  float f[8]; u32 v;
  point_feats(p, pts, lin, counts, vsum, f, &v);
  __shared__ float lsum[4][8], lsq[4][8];
  int lane = threadIdx.x & 63, wv = threadIdx.x >> 6;
  #pragma unroll
  for(int c=0;c<8;c++){
    float s = f[c], q = f[c]*f[c];
    #pragma unroll
    for(int d=32; d; d>>=1){ s += __shfl_xor(s,d); q += __shfl_xor(q,d); }
    if(lane==0){ lsum[wv][c]=s; lsq[wv][c]=q; }
  }
  __syncthreads();
  if(threadIdx.x<8){
    float s=0.f,q=0.f;
    for(int g=0;g<4;g++){ s+=lsum[g][threadIdx.x]; q+=lsq[g][threadIdx.x]; }
    atomicAdd(&sum0[threadIdx.x], s);
    atomicAdd(&sq0[threadIdx.x], q);
  }
}

// ---------------- fold BN stats -> (a,c) (proven) ----------------
__global__ void k_fold(const float* __restrict__ sum, const float* __restrict__ sq,
                       const float* __restrict__ g, const float* __restrict__ b,
                       float* __restrict__ a, float* __restrict__ c, int C){
  int i = blockIdx.x*64 + threadIdx.x;
  if(i < C){
    float m = sum[i]*(1.0f/NPTS);
    float v = sq[i]*(1.0f/NPTS) - m*m;
    v = fmaxf(v, 0.0f);
    float ai = g[i] / sqrtf(v + EPSV);
    a[i] = ai;
    c[i] = b[i] - m*ai;
  }
}

// ---------------- stats1 (scalar, proven) ----------------
__global__ __launch_bounds__(256) void k_stats1(const float* __restrict__ pts,
    const u32* __restrict__ lin, const u32* __restrict__ counts,
    const float* __restrict__ vsum,
    const float* __restrict__ a0, const float* __restrict__ c0,
    const float* __restrict__ W1, float* __restrict__ sum1, float* __restrict__ sq1){
  __shared__ float ws[4][64], wq[4][64];
  int t = threadIdx.x;
  int p = blockIdx.x*256 + t;
  float f[8]; u32 v;
  point_feats(p, pts, lin, counts, vsum, f, &v);
  float y0[8];
  #pragma unroll
  for(int k=0;k<8;k++) y0[k] = a0[k]*f[k] + c0[k];
  float z[64];
  #pragma unroll
  for(int j=0;j<64;j++){
    float s=0.f;
    #pragma unroll
    for(int k=0;k<8;k++) s += y0[k]*W1[k*64+j];
    z[j]=s;
  }
  int lane = t&63, wv = t>>6;
  float ks=0.f, kq=0.f;
  #pragma unroll
  for(int c=0;c<64;c++){
    float s=z[c], q=z[c]*z[c];
    #pragma unroll
    for(int d=1; d<64; d<<=1){ s+=__shfl_xor(s,d); q+=__shfl_xor(q,d); }
    if(lane==c){ ks=s; kq=q; }
  }
  ws[wv][lane]=ks; wq[wv][lane]=kq;
  __syncthreads();
  if(t<64){
    float S=ws[0][t]+ws[1][t]+ws[2][t]+ws[3][t];
    float Q=wq[0][t]+wq[1][t]+wq[2][t]+wq[3][t];
    atomicAdd(&sum1[t],S); atomicAdd(&sq1[t],Q);
  }
}

// ---------------- mstats2: z2 stats via MFMA (proven) ----------
__global__ __launch_bounds__(256,2) void k_mstats2(
    const float* __restrict__ pts, const u32* __restrict__ lin,
    const u32* __restrict__ counts, const float* __restrict__ vsum,
    const float* __restrict__ a0, const float* __restrict__ c0,
    const float* __restrict__ a1, const float* __restrict__ c1,
    const float* __restrict__ W1, const u16* __restrict__ W2t,
    float* __restrict__ sum2, float* __restrict__ sq2){
  __shared__ u16 T1[256*72];
  int tid = threadIdx.x, lane = tid&63, wid = tid>>6, l15 = lane&15, lg = lane>>4;
  float s2[2] = {0.f,0.f}, q2[2] = {0.f,0.f};

  for(int cch=0; cch<4; cch++){
    int p = blockIdx.x*1024 + cch*256 + tid;
    float f[8]; u32 v;
    point_feats(p, pts, lin, counts, vsum, f, &v);
    float y0[8];
    #pragma unroll
    for(int k=0;k<8;k++) y0[k] = a0[k]*f[k] + c0[k];
    u32 pk[32];
    #pragma unroll
    for(int jj=0;jj<32;jj++){
      float s0=0.f, s1=0.f;
      #pragma unroll
      for(int k=0;k<8;k++){ s0 += y0[k]*W1[k*64+2*jj]; s1 += y0[k]*W1[k*64+2*jj+1]; }
      float v0f = fmaxf(a1[2*jj]*s0   + c1[2*jj],   0.f);
      float v1f = fmaxf(a1[2*jj+1]*s1 + c1[2*jj+1], 0.f);
      pk[jj] = (u32)f2bf(v0f) | ((u32)f2bf(v1f)<<16);
    }
    __syncthreads();
    {
      uint4* dst = (uint4*)&T1[tid*72];
      #pragma unroll
      for(int q=0;q<8;q++) dst[q] = make_uint4(pk[4*q],pk[4*q+1],pk[4*q+2],pk[4*q+3]);
    }
    __syncthreads();
    #pragma unroll
    for(int ci=0; ci<2; ci++){
      int ch = (wid + 4*ci)*16 + l15;
      const u16* wb = W2t + (size_t)ch*64 + lg*8;
      bf16x8 b0 = *(const bf16x8*)(wb);
      bf16x8 b1 = *(const bf16x8*)(wb + 32);
      for(int rt=0; rt<16; rt++){
        const u16* ap = T1 + (rt*16 + l15)*72 + lg*8;
        bf16x8 af0 = *(const bf16x8*)(ap);
        bf16x8 af1 = *(const bf16x8*)(ap + 32);
        f32x4 acc = {0.f,0.f,0.f,0.f};
        acc = __builtin_amdgcn_mfma_f32_16x16x32_bf16(af0, b0, acc, 0,0,0);
        acc = __builtin_amdgcn_mfma_f32_16x16x32_bf16(af1, b1, acc, 0,0,0);
        #pragma unroll
        for(int i=0;i<4;i++){ s2[ci] += acc[i]; q2[ci] += acc[i]*acc[i]; }
      }
    }
  }
  #pragma unroll
  for(int ci=0; ci<2; ci++){
    float s = s2[ci], q = q2[ci];
    s += __shfl_xor(s,16); s += __shfl_xor(s,32);
    q += __shfl_xor(q,16); q += __shfl_xor(q,32);
    if(lg == 0){
      int ch = (wid + 4*ci)*16 + l15;
      atomicAdd(&sum2[ch], s);
      atomicAdd(&sq2[ch], q);
    }
  }
}

// ---------------- chain2: sorted-order chain, z3 stats + y2s dump (proven) -------
__global__ __launch_bounds__(256,1) void k_chain2(
    const float* __restrict__ pts, const u32* __restrict__ lin,
    const u32* __restrict__ counts, const float* __restrict__ vsum,
    const u32* __restrict__ order,
    const float* __restrict__ a0, const float* __restrict__ c0,
    const float* __restrict__ a1, const float* __restrict__ c1,
    const float* __restrict__ a2, const float* __restrict__ c2,
    const float* __restrict__ W1, const u16* __restrict__ W2t,
    const u16* __restrict__ W3t,
    u32* __restrict__ y2s,
    float* __restrict__ sum3, float* __restrict__ sq3){
  __shared__ u16 T1[256*72];
  __shared__ u16 T2[256*136];
  int tid = threadIdx.x, lane = tid&63, wid = tid>>6, l15 = lane&15, lg = lane>>4;
  float s3[4] = {0.f,0.f,0.f,0.f}, q3[4] = {0.f,0.f,0.f,0.f};

  for(int cch=0; cch<4; cch++){
    int rr = blockIdx.x*1024 + cch*256 + tid;   // sorted row index
    int p = (int)order[rr];
    float f[8]; u32 v;
    point_feats(p, pts, lin, counts, vsum, f, &v);
    float y0[8];
    #pragma unroll
    for(int k=0;k<8;k++) y0[k] = a0[k]*f[k] + c0[k];
    u32 pk[32];
    #pragma unroll
    for(int jj=0;jj<32;jj++){
      float s0=0.f, s1=0.f;
      #pragma unroll
      for(int k=0;k<8;k++){ s0 += y0[k]*W1[k*64+2*jj]; s1 += y0[k]*W1[k*64+2*jj+1]; }
      float v0f = fmaxf(a1[2*jj]*s0   + c1[2*jj],   0.f);
      float v1f = fmaxf(a1[2*jj+1]*s1 + c1[2*jj+1], 0.f);
      pk[jj] = (u32)f2bf(v0f) | ((u32)f2bf(v1f)<<16);
    }
    __syncthreads();
    {
      uint4* dst = (uint4*)&T1[tid*72];
      #pragma unroll
      for(int q=0;q<8;q++) dst[q] = make_uint4(pk[4*q],pk[4*q+1],pk[4*q+2],pk[4*q+3]);
    }
    __syncthreads();
    #pragma unroll
    for(int ci=0; ci<2; ci++){
      int ch = (wid + 4*ci)*16 + l15;
      const u16* wb = W2t + (size_t)ch*64 + lg*8;
      bf16x8 b0 = *(const bf16x8*)(wb);
      bf16x8 b1 = *(const bf16x8*)(wb + 32);
      float a2v = a2[ch], c2v = c2[ch];
      for(int rt=0; rt<16; rt++){
        const u16* ap = T1 + (rt*16 + l15)*72 + lg*8;
        bf16x8 af0 = *(const bf16x8*)(ap);
        bf16x8 af1 = *(const bf16x8*)(ap + 32);
        f32x4 acc = {0.f,0.f,0.f,0.f};
        acc = __builtin_amdgcn_mfma_f32_16x16x32_bf16(af0, b0, acc, 0,0,0);
        acc = __builtin_amdgcn_mfma_f32_16x16x32_bf16(af1, b1, acc, 0,0,0);
        int rbase = rt*16 + lg*4;
        #pragma unroll
        for(int i=0;i<4;i++)
          T2[(rbase+i)*136 + ch] = f2bf(fmaxf(a2v*acc[i] + c2v, 0.f));
      }
    }
    __syncthreads();
    {
      const u32* T2w = (const u32*)T2;
      u32 base = (u32)blockIdx.x*1024u + (u32)cch*256u;
      for(int i=tid; i<256*64; i+=256){
        int row = i>>6, w = i&63;
        y2s[(size_t)(base+row)*64 + w] = T2w[row*68 + w];
      }
    }
    #pragma unroll
    for(int ci=0; ci<4; ci++){
      int ch = (wid + 4*ci)*16 + l15;
      const u16* wb = W3t + (size_t)ch*128 + lg*8;
      bf16x8 b[4];
      #pragma unroll
      for(int ks=0; ks<4; ks++) b[ks] = *(const bf16x8*)(wb + ks*32);
      for(int rt=0; rt<16; rt++){
        const u16* ap = T2 + (rt*16 + l15)*136 + lg*8;
        f32x4 acc = {0.f,0.f,0.f,0.f};
        #pragma unroll
        for(int ks=0; ks<4; ks++){
          bf16x8 af = *(const bf16x8*)(ap + ks*32);
          acc = __builtin_amdgcn_mfma_f32_16x16x32_bf16(af, b[ks], acc, 0,0,0);
        }
        #pragma unroll
        for(int i=0;i<4;i++){ s3[ci] += acc[i]; q3[ci] += acc[i]*acc[i]; }
      }
    }
  }
  #pragma unroll
  for(int ci=0; ci<4; ci++){
    float s = s3[ci], q = q3[ci];
    s += __shfl_xor(s,16); s += __shfl_xor(s,32);
    q += __shfl_xor(q,16); q += __shfl_xor(q,32);
    if(lg == 0){
      int ch = (wid + 4*ci)*16 + l15;
      atomicAdd(&sum3[ch], s);
      atomicAdd(&sq3[ch], q);
    }
  }
}

// ---------------- k_z4b: rows [offsets[vbase], offsets[vend]) -> z4 row-major ----
// 512 threads, 128 rows/block. LDS = T3 only (67.6 KB -> 2 blocks/CU). 1 barrier.
__global__ __launch_bounds__(512,2) void k_z4b(
    const u32* __restrict__ y2s, const u32* __restrict__ offsets,
    u32 vbase, u32 vend, u32 caprows,
    const float* __restrict__ a3, const float* __restrict__ c3,
    const u16* __restrict__ W3t, const u16* __restrict__ W4t,
    u16* __restrict__ z4){
  __shared__ u16 T3[128*264];   // 67584 B
  int tid = threadIdx.x, lane = tid & 63, wid = tid >> 6;
  int l15 = lane & 15, lg = lane >> 4;
  u32 rlo = offsets[vbase], rhi = offsets[vend];
  u32 rows = rhi - rlo; if(rows > caprows) rows = caprows;
  u32 row0 = (u32)blockIdx.x * 128u;
  if(row0 >= rows) return;

  // L3: y2 (global A-frags, rows rlo+row0+..) @ W3t -> bn3relu -> T3
  for(int ci=0; ci<2; ci++){
    int ch = (wid + 8*ci)*16 + l15;
    const u16* wb = W3t + (size_t)ch*128 + lg*8;
    bf16x8 b[4];
    #pragma unroll
    for(int ks=0; ks<4; ks++) b[ks] = *(const bf16x8*)(wb + ks*32);
    float a3v = a3[ch], c3v = c3[ch];
    for(int rt=0; rt<8; rt++){
      const u16* ap = (const u16*)y2s + ((size_t)rlo + row0 + rt*16 + l15)*128 + lg*8;
      f32x4 acc = {0.f,0.f,0.f,0.f};
      #pragma unroll
      for(int ks=0; ks<4; ks++){
        bf16x8 af = *(const bf16x8*)(ap + ks*32);
        acc = __builtin_amdgcn_mfma_f32_16x16x32_bf16(af, b[ks], acc, 0,0,0);
      }
      int rbase = rt*16 + lg*4;
      #pragma unroll
      for(int i=0;i<4;i++)
        T3[(rbase+i)*264 + ch] = f2bf(fmaxf(a3v*acc[i] + c3v, 0.f));
    }
  }
  __syncthreads();

  // L4: T3 @ W4t -> z4[(row)*256 + ch] bf16, guarded
  for(int ci=0; ci<2; ci++){
    int ch = (wid + 8*ci)*16 + l15;
    const u16* wb = W4t + (size_t)ch*256 + lg*8;
    bf16x8 b[8];
    #pragma unroll
    for(int ks=0; ks<8; ks++) b[ks] = *(const bf16x8*)(wb + ks*32);
    for(int rt=0; rt<8; rt++){
      const u16* ap = T3 + (rt*16 + l15)*264 + lg*8;
      f32x4 acc = {0.f,0.f,0.f,0.f};
      #pragma unroll
      for(int ks=0; ks<8; ks++){
        bf16x8 af = *(const bf16x8*)(ap + ks*32);
        acc = __builtin_amdgcn_mfma_f32_16x16x32_bf16(af, b[ks], acc, 0,0,0);
      }
      u32 rb = row0 + (u32)(rt*16 + lg*4);
      #pragma unroll
      for(int i=0;i<4;i++){
        u32 r = rb + (u32)i;
        if(r < rows) z4[(size_t)r*256 + ch] = f2bf(acc[i]);
      }
    }
  }
}

// ---------------- k_segcompb: segmax (row-major z4) + comp GEMM ------------------
// 256 threads, 64 voxels/block. Thread tid = channel; (v,r) loop uniform ->
// each read step = 256 threads x 2B = one coalesced 512B z4 row.
__global__ __launch_bounds__(256,4) void k_segcompb(
    const u32* __restrict__ offsets, const u16* __restrict__ z4, u32 vbase,
    const float* __restrict__ b4, const u16* __restrict__ Wct,
    const float* __restrict__ bc, u16* __restrict__ comp){
  __shared__ u16 TA[64*264];    // 33792 B
  __shared__ u32 voff[65];
  __shared__ float bb[256];
  int tid = threadIdx.x, lane = tid & 63, wid = tid >> 6;
  int l15 = lane & 15, lg = lane >> 4;
  u32 v0 = vbase + (u32)blockIdx.x * 64u;

  if(tid < 65) voff[tid] = offsets[v0 + tid];
  bb[tid] = b4[tid];
  u32 rlo = offsets[vbase];
  __syncthreads();

  {
    int k = tid;
    for(int v=0; v<64; v++){
      u32 r0 = voff[v], r1 = voff[v+1];
      u16 o = 0;
      if(r1 > r0){
        float m = -3.0e38f;
        for(u32 r=r0; r<r1; r++) m = fmaxf(m, bf2f(z4[(size_t)(r - rlo)*256 + k]));
        o = f2bf(m + bb[k]);
      }
      TA[v*264 + k] = o;
    }
  }
  __syncthreads();

  // comp GEMM: TA(64x256) @ Wct -> relu(+bc)*nz -> comp
  int ch4 = wid*16 + l15;
  const u16* wb = Wct + (size_t)ch4*256 + lg*8;
  bf16x8 b[8];
  #pragma unroll
  for(int ks=0; ks<8; ks++) b[ks] = *(const bf16x8*)(wb + ks*32);
  float bcv = bc[ch4];
  #pragma unroll
  for(int vt=0; vt<4; vt++){
    const u16* ap = TA + (vt*16 + l15)*264 + lg*8;
    f32x4 acc = {0.f,0.f,0.f,0.f};
    #pragma unroll
    for(int ks=0; ks<8; ks++){
      bf16x8 af = *(const bf16x8*)(ap + ks*32);
      acc = __builtin_amdgcn_mfma_f32_16x16x32_bf16(af, b[ks], acc, 0,0,0);
    }
    int vbaseL = vt*16 + lg*4;
    #pragma unroll
    for(int i=0;i<4;i++){
      int vox = vbaseL + i;
      bool nz = voff[vox+1] > voff[vox];
      float val = nz ? fmaxf(acc[i] + bcv, 0.f) : 0.f;
      comp[(size_t)(v0+vox)*64 + ch4] = f2bf(val);
    }
  }
}

// ---------------- mega4 (proven fallback; loop-tail barrier trimmed) -------------
__global__ __launch_bounds__(256,2) void k_mega4(
    const u32* __restrict__ offsets, const u32* __restrict__ y2s,
    const float* __restrict__ a3, const float* __restrict__ c3,
    const u16* __restrict__ W3t, const u16* __restrict__ W4t,
    const u16* __restrict__ Wct,
    const float* __restrict__ b4, const float* __restrict__ bc,
    u16* __restrict__ comp){
  __shared__ __align__(16) char SM[65664];
  u16* T3  = (u16*)(SM);
  u16* T2s = (u16*)(SM + 42240);
  u16* Tz  = (u16*)(SM + 42240);
  u16* TA  = (u16*)(SM + 53760);
  u32* vst = (u32*)(SM + 65280);
  u32* hdr = (u32*)(SM + 65616);

  int tid = threadIdx.x, lane = tid & 63, wid = tid >> 6;
  int l15 = lane & 15, lg = lane >> 4;

  if(tid == 0){
    u32 t0 = (u32)blockIdx.x * 64u;
    u32 lo=0, hi=SS;
    while(lo<hi){ u32 mid=(lo+hi)>>1; if(offsets[mid] < t0) lo=mid+1; else hi=mid; }
    u32 vlo = lo, vhi;
    if(blockIdx.x == NB-1) vhi = SS;
    else {
      u32 t1 = t0 + 64u;
      lo = vlo; hi = SS;
      while(lo<hi){ u32 mid=(lo+hi)>>1; if(offsets[mid] < t1) lo=mid+1; else hi=mid; }
      vhi = lo;
    }
    hdr[0]=vlo; hdr[1]=vhi; hdr[2]=offsets[vlo]; hdr[3]=offsets[vhi];
  }
  __syncthreads();
  u32 vlo=hdr[0], vhi=hdr[1], start=hdr[2], end=hdr[3];
  int R = (int)(end - start); if(R > RCAP) R = RCAP;
  int V = (int)(vhi - vlo);   if(V > VCAP) V = VCAP;

  if(tid <= VCAP){
    u32 o = (tid <= V) ? offsets[vlo + tid] : end;
    int s = (int)(o - start); if(s > RCAP) s = RCAP;
    vst[tid] = (u32)s;
  }

  {
    u32* T2w = (u32*)T2s;
    for(int i=tid; i<RCAP*64; i+=256){
      int row = i>>6, w = i&63;
      u32 val = (row < R) ? y2s[(size_t)(start+row)*64 + w] : 0u;
      T2w[row*68 + w] = val;
    }
  }
  __syncthreads();

  for(int ci=0; ci<4; ci++){
    int ch = (wid + 4*ci)*16 + l15;
    const u16* wb = W3t + (size_t)ch*128 + lg*8;
    bf16x8 b[4];
    #pragma unroll
    for(int ks=0; ks<4; ks++) b[ks] = *(const bf16x8*)(wb + ks*32);
    float a3v = a3[ch], c3v = c3[ch];
    for(int rt=0; rt<5; rt++){
      const u16* ap = T2s + (rt*16 + l15)*136 + lg*8;
      f32x4 acc = {0.f,0.f,0.f,0.f};
      #pragma unroll
      for(int ks=0; ks<4; ks++){
        bf16x8 af = *(const bf16x8*)(ap + ks*32);
        acc = __builtin_amdgcn_mfma_f32_16x16x32_bf16(af, b[ks], acc, 0,0,0);
      }
      int rbase = rt*16 + lg*4;
      #pragma unroll
      for(int i=0;i<4;i++)
        T3[(rbase+i)*264 + ch] = f2bf(fmaxf(a3v*acc[i] + c3v, 0.f));
    }
  }
  __syncthreads();

  f32x4 acc5[5];
  #pragma unroll
  for(int i=0;i<5;i++) acc5[i] = (f32x4){0.f,0.f,0.f,0.f};
  int ch4 = wid*16 + l15;

  for(int oc=0; oc<4; oc++){
    // z4 chunk -> Tz (Tz/TA disjoint; comp(oc-1) ran concurrently before this)
    {
      int chg = oc*64 + ch4;
      const u16* wb = W4t + (size_t)chg*256 + lg*8;
      bf16x8 b[8];
      #pragma unroll
      for(int ks=0; ks<8; ks++) b[ks] = *(const bf16x8*)(wb + ks*32);
      for(int rt=0; rt<5; rt++){
        const u16* ap = T3 + (rt*16 + l15)*264 + lg*8;
        f32x4 acc = {0.f,0.f,0.f,0.f};
        #pragma unroll
        for(int ks=0; ks<8; ks++){
          bf16x8 af = *(const bf16x8*)(ap + ks*32);
          acc = __builtin_amdgcn_mfma_f32_16x16x32_bf16(af, b[ks], acc, 0,0,0);
        }
        int rbase = rt*16 + lg*4;
        #pragma unroll
        for(int i=0;i<4;i++)
          Tz[(rbase+i)*72 + ch4] = f2bf(acc[i]);
      }
    }
    __syncthreads();
    for(int i=tid; i<VCAP*64; i+=256){
      int v = i>>6, k = i&63;
      u32 r0 = vst[v], r1 = vst[v+1];
      u16 outv = 0;
      if(r1 > r0){
        float m = -3.0e38f;
        for(u32 r=r0; r<r1; r++) m = fmaxf(m, bf2f(Tz[r*72+k]));
        outv = f2bf(m + b4[oc*64+k]);
      }
      TA[v*72+k] = outv;
    }
    __syncthreads();
    {
      const u16* wb = Wct + (size_t)ch4*256 + oc*64 + lg*8;
      bf16x8 b0 = *(const bf16x8*)(wb);
      bf16x8 b1 = *(const bf16x8*)(wb + 32);
      #pragma unroll
      for(int vt=0; vt<5; vt++){
        const u16* ap = TA + (vt*16 + l15)*72 + lg*8;
        bf16x8 af0 = *(const bf16x8*)(ap);
        bf16x8 af1 = *(const bf16x8*)(ap + 32);
        acc5[vt] = __builtin_amdgcn_mfma_f32_16x16x32_bf16(af0, b0, acc5[vt], 0,0,0);
        acc5[vt] = __builtin_amdgcn_mfma_f32_16x16x32_bf16(af1, b1, acc5[vt], 0,0,0);
      }
    }
    // no tail barrier: next z4 writes Tz (disjoint from TA); top barrier guards Tz
  }

  {
    float bcv = bc[ch4];
    #pragma unroll
    for(int vt=0; vt<5; vt++){
      int vbase = vt*16 + lg*4;
      #pragma unroll
      for(int i=0;i<4;i++){
        int vox = vbase + i;
        if(vox < V){
          bool nz = vst[vox+1] > vst[vox];
          float val = nz ? fmaxf(acc5[vt][i] + bcv, 0.f) : 0.f;
          comp[(size_t)(vlo+vox)*64 + ch4] = f2bf(val);
        }
      }
    }
  }
}

// ---------------- residual image from comp (proven) ----------------
__global__ __launch_bounds__(256) void k_resid(const u16* __restrict__ comp,
                                               float* __restrict__ out){
  __shared__ u32 cl[4*128*32];
  int t = threadIdx.x;
  int blk = blockIdx.x;
  int wq = blk & 3, h = (blk>>2) & 63, b = blk>>8;
  int w0 = wq*128;
  for(int fr=0; fr<4; fr++){
    const u32* src = (const u32*)comp + ((size_t)(((b*4+fr)*64 + h)*512 + w0))*32;
    for(int i=t; i<4096; i+=256){
      int vox = i>>5, wd = i&31;
      cl[fr*4096 + vox*32 + (wd ^ (vox&31))] = src[i];
    }
  }
  __syncthreads();
  int wl = t & 127, half = t >> 7;
  int mv = wl & 31;
  for(int ch = half; ch < 64; ch += 2){
    u32 wr3 = cl[3*4096 + wl*32 + ((ch>>1) ^ mv)];
    float r3 = bf2f((ch&1) ? (u16)(wr3>>16) : (u16)(wr3&0xFFFFu));
    #pragma unroll
    for(int fr=0; fr<3; fr++){
      u32 wrf = cl[fr*4096 + wl*32 + ((ch>>1) ^ mv)];
      float vf = bf2f((ch&1) ? (u16)(wrf>>16) : (u16)(wrf&0xFFFFu));
      out[(((size_t)(b*192 + fr*64 + ch))*64 + h)*512 + w0 + wl] = r3 - vf;
    }
  }
}

// ------------------------------- launcher -------------------------------------
extern "C" void kernel_launch(void* const* d_in, const int* in_sizes, int n_in,
                              void* d_out, int out_size, void* d_ws, size_t ws_size,
                              hipStream_t stream){
  const float* pts  = (const float*)d_in[0];
  const int*  coors = (const int*)d_in[1];
  const float* g0 = (const float*)d_in[2];
  const float* b0 = (const float*)d_in[3];
  const float* W1 = (const float*)d_in[4];
  const float* g1 = (const float*)d_in[5];
  const float* b1 = (const float*)d_in[6];
  const float* W2 = (const float*)d_in[7];
  const float* g2 = (const float*)d_in[8];
  const float* b2 = (const float*)d_in[9];
  const float* W3 = (const float*)d_in[10];
  const float* g3 = (const float*)d_in[11];
  const float* b3 = (const float*)d_in[12];
  const float* W4 = (const float*)d_in[13];
  const float* b4 = (const float*)d_in[14];
  const float* Wc = (const float*)d_in[15];
  const float* bc = (const float*)d_in[16];
  float* out = (float*)d_out;
  (void)in_sizes; (void)n_in; (void)out_size;

  char* ws = (char*)d_ws;
  size_t off = 0;
  auto alloc = [&](size_t bytes)->void*{
    void* p = ws + off;
    off += (bytes + 255) & ~(size_t)255;
    return p;
  };
  u32*  counts  = (u32*)alloc((size_t)SS*4);
  float* vsum   = (float*)alloc((size_t)SS*3*4);
  float* stats  = (float*)alloc(8192);
  size_t zero_bytes = off;
  u32*  lin     = (u32*)alloc((size_t)NPTS*4);
  u32*  offsets = (u32*)alloc((size_t)(SS+1)*4);
  u32*  cursor  = (u32*)alloc((size_t)SS*4);
  u32*  order   = (u32*)alloc((size_t)NPTS*4);
  u32*  blockSums = (u32*)alloc(1024);
  u16*  comp    = (u16*)alloc((size_t)SS*64*2);
  u16*  W2t = (u16*)alloc(8192*2);
  u16*  W3t = (u16*)alloc(32768*2);
  u16*  W4t = (u16*)alloc(65536*2);
  u16*  Wct = (u16*)alloc(16384*2);
  u32*  y2s = (u32*)alloc((size_t)NPTS*64*4);   // 134 MB (proven budget)

  // z4 ladder: NE=8 (37.7 MB) -> NE=16 (21 MB) -> fallback mega4
  int NE = 0; u32 caprows = 0; u16* z4buf = (u16*)(ws + off);
  {
    size_t cap8  = (size_t)(NPTS/8  + 8192);
    size_t cap16 = (size_t)(NPTS/16 + 8192);
    if(off + cap8*512  <= ws_size){ NE = 8;  caprows = (u32)cap8; }
    else if(off + cap16*512 <= ws_size){ NE = 16; caprows = (u32)cap16; }
  }

  float* sum0=stats+0,   *sq0=stats+8,    *a0=stats+16,   *c0=stats+24;
  float* sum1=stats+32,  *sq1=stats+96,   *a1=stats+160,  *c1=stats+224;
  float* sum2=stats+288, *sq2=stats+416,  *a2=stats+544,  *c2=stats+672;
  float* sum3=stats+800, *sq3=stats+1056, *a3=stats+1312, *c3=stats+1568;

  hipMemsetAsync(d_ws, 0, zero_bytes, stream);

  k_prep   <<<480, 256,0,stream>>>(W2, W3, W4, Wc, W2t, W3t, W4t, Wct);
  k_lin    <<<2048,256,0,stream>>>(pts, coors, lin, counts, vsum);
  k_scan_a <<<256, 256,0,stream>>>(counts, blockSums);
  k_scan_b <<<1,   64, 0,stream>>>(blockSums);
  k_scan_c <<<256, 256,0,stream>>>(counts, blockSums, offsets, cursor);
  k_scatter<<<2048,256,0,stream>>>(lin, cursor, order);

  k_stats0 <<<2048,256,0,stream>>>(pts, lin, counts, vsum, sum0, sq0);
  k_fold   <<<1,   64, 0,stream>>>(sum0, sq0, g0, b0, a0, c0, 8);
  k_stats1 <<<2048,256,0,stream>>>(pts, lin, counts, vsum, a0, c0, W1, sum1, sq1);
  k_fold   <<<1,   64, 0,stream>>>(sum1, sq1, g1, b1, a1, c1, 64);
  k_mstats2<<<512, 256,0,stream>>>(pts, lin, counts, vsum, a0,c0,a1,c1, W1, W2t, sum2, sq2);
  k_fold   <<<2,   64, 0,stream>>>(sum2, sq2, g2, b2, a2, c2, 128);
  k_chain2 <<<512, 256,0,stream>>>(pts, lin, counts, vsum, order,
                                   a0,c0,a1,c1,a2,c2, W1, W2t, W3t,
                                   y2s, sum3, sq3);
  k_fold   <<<4,   64, 0,stream>>>(sum3, sq3, g3, b3, a3, c3, 256);

  if(NE > 0){
    u32 vstep = (u32)(SS / NE);
    int gz = (int)((caprows + 127) / 128);
    int gv = (int)(vstep / 64);
    for(int e=0; e<NE; e++){
      u32 vb = (u32)e * vstep, ve = vb + vstep;
      k_z4b     <<<gz, 512,0,stream>>>(y2s, offsets, vb, ve, caprows,
                                       a3, c3, W3t, W4t, z4buf);
      k_segcompb<<<gv, 256,0,stream>>>(offsets, z4buf, vb, b4, Wct, bc, comp);
    }
  } else {
    k_mega4  <<<NB,  256,0,stream>>>(offsets, y2s, a3,c3, W3t, W4t, Wct, b4, bc, comp);
  }
  k_resid  <<<512, 256,0,stream>>>(comp, out);
}

// Round 10
// 1105.536 us; speedup vs baseline: 1.7140x; 1.7140x over previous
//
#include <hip/hip_runtime.h>
#include <hip/hip_bf16.h>
#include <stdint.h>

typedef unsigned int u32;
typedef unsigned short u16;
typedef __attribute__((ext_vector_type(8))) short bf16x8;
typedef __attribute__((ext_vector_type(4))) float f32x4;

#define NPTS 524288
#define FF 4
#define HH 64
#define WW 512
#define SS 262144
#define EPSV 1e-5f
#define NB 8192      // 64 points per block (mega5)
#define RCAP 80
#define VCAP 80

__device__ __forceinline__ float bf2f(u16 h){ return __uint_as_float(((u32)h)<<16); }
__device__ __forceinline__ u16 f2bf(float f){
  u32 u = __float_as_uint(f);
  return (u16)((u + 0x7FFFu + ((u>>16)&1u)) >> 16);   // RNE (monotone)
}

__device__ __forceinline__ void point_feats(int p, const float* __restrict__ pts,
    const u32* __restrict__ lin, const u32* __restrict__ counts,
    const float* __restrict__ vsum, float f[8], u32* vout){
  float4 pt = ((const float4*)pts)[p];
  u32 v = lin[p];
  float cnt = fmaxf((float)counts[v], 1.0f);
  float inv = 1.0f/cnt;
  float mx = vsum[v*3+0]*inv, my = vsum[v*3+1]*inv, mz = vsum[v*3+2]*inv;
  float dist = sqrtf(pt.x*pt.x + pt.y*pt.y + pt.z*pt.z);
  f[0]=pt.x; f[1]=pt.y; f[2]=pt.z; f[3]=pt.w; f[4]=dist;
  f[5]=pt.x-mx; f[6]=pt.y-my; f[7]=pt.z-mz;
  *vout = v;
}

// ---------------- pass 1: linear voxel id + counts + coord sums ----------------
__global__ __launch_bounds__(256) void k_lin(const float* __restrict__ pts,
                                             const int* __restrict__ coors,
                                             u32* __restrict__ lin,
                                             u32* __restrict__ counts,
                                             float* __restrict__ vsum){
  int p = blockIdx.x*256 + threadIdx.x;
  int4 c = ((const int4*)coors)[p];
  u32 v = ((u32)((c.x*FF + c.y)*HH + c.z))*WW + (u32)c.w;
  lin[p] = v;
  atomicAdd(&counts[v], 1u);
  float4 pt = ((const float4*)pts)[p];
  atomicAdd(&vsum[v*3+0], pt.x);
  atomicAdd(&vsum[v*3+1], pt.y);
  atomicAdd(&vsum[v*3+2], pt.z);
}

// ---------------- counting-sort scan ----------------
__global__ __launch_bounds__(256) void k_scan_a(const u32* __restrict__ counts,
                                                u32* __restrict__ blockSums){
  __shared__ u32 lds[256];
  int b = blockIdx.x, t = threadIdx.x;
  uint4 c4 = ((const uint4*)counts)[b*256 + t];
  lds[t] = c4.x + c4.y + c4.z + c4.w;
  __syncthreads();
  for(int s=128; s>0; s>>=1){ if(t<s) lds[t] += lds[t+s]; __syncthreads(); }
  if(t==0) blockSums[b] = lds[0];
}

__global__ void k_scan_b(u32* blockSums){
  if(threadIdx.x==0){
    u32 run = 0;
    for(int i=0;i<256;i++){ u32 v = blockSums[i]; blockSums[i] = run; run += v; }
  }
}

__global__ __launch_bounds__(256) void k_scan_c(const u32* __restrict__ counts,
                                                const u32* __restrict__ blockSums,
                                                u32* __restrict__ offsets,
                                                u32* __restrict__ cursor){
  __shared__ u32 lds[256];
  int b = blockIdx.x, t = threadIdx.x;
  uint4 c4 = ((const uint4*)counts)[b*256 + t];
  u32 mysum = c4.x + c4.y + c4.z + c4.w;
  lds[t] = mysum;
  __syncthreads();
  for(int d=1; d<256; d<<=1){
    u32 v = (t>=d) ? lds[t-d] : 0u;
    __syncthreads();
    lds[t] += v;
    __syncthreads();
  }
  u32 off = blockSums[b] + (t>0 ? lds[t-1] : 0u);
  u32 base = (u32)(b*1024 + t*4);
  offsets[base+0]=off; cursor[base+0]=off; off += c4.x;
  offsets[base+1]=off; cursor[base+1]=off; off += c4.y;
  offsets[base+2]=off; cursor[base+2]=off; off += c4.z;
  offsets[base+3]=off; cursor[base+3]=off; off += c4.w;
  if(base+4 == SS) offsets[SS] = off;
}

__global__ __launch_bounds__(256) void k_scatter(const u32* __restrict__ lin,
                                                 u32* __restrict__ cursor,
                                                 u32* __restrict__ order){
  int p = blockIdx.x*256 + threadIdx.x;
  u32 v = lin[p];
  u32 pos = atomicAdd(&cursor[v], 1u);
  order[pos] = p;
}

// ---------------- weight prep: bf16 transposed ----------------
__global__ __launch_bounds__(256) void k_prep(const float* __restrict__ W2,
    const float* __restrict__ W3, const float* __restrict__ W4,
    const float* __restrict__ Wc,
    u16* __restrict__ W2t, u16* __restrict__ W3t, u16* __restrict__ W4t,
    u16* __restrict__ Wct){
  int i = blockIdx.x*256 + threadIdx.x;
  if(i < 8192){
    int k = i >> 7, n = i & 127;
    W2t[n*64 + k] = f2bf(W2[i]);
  } else if(i < 8192+32768){
    int j = i - 8192;
    int k = j >> 8, n = j & 255;
    W3t[n*128 + k] = f2bf(W3[j]);
  } else if(i < 8192+32768+65536){
    int j = i - (8192+32768);
    int k = j >> 8, n = j & 255;
    W4t[n*256 + k] = f2bf(W4[j]);
  } else if(i < 8192+32768+65536+16384){
    int j = i - (8192+32768+65536);
    int k = j >> 6, n = j & 63;
    Wct[n*256 + k] = f2bf(Wc[j]);
  }
}

// ---------------- stats0 (proven) ----------------
__global__ __launch_bounds__(256) void k_stats0(const float* __restrict__ pts,
    const u32* __restrict__ lin, const u32* __restrict__ counts,
    const float* __restrict__ vsum, float* __restrict__ sum0, float* __restrict__ sq0){
  int p = blockIdx.x*256 + threadIdx.x;
  float f[8]; u32 v;
  point_feats(p, pts, lin, counts, vsum, f, &v);
  __shared__ float lsum[4][8], lsq[4][8];
  int lane = threadIdx.x & 63, wv = threadIdx.x >> 6;
  #pragma unroll
  for(int c=0;c<8;c++){
    float s = f[c], q = f[c]*f[c];
    #pragma unroll
    for(int d=32; d; d>>=1){ s += __shfl_xor(s,d); q += __shfl_xor(q,d); }
    if(lane==0){ lsum[wv][c]=s; lsq[wv][c]=q; }
  }
  __syncthreads();
  if(threadIdx.x<8){
    float s=0.f,q=0.f;
    for(int g=0;g<4;g++){ s+=lsum[g][threadIdx.x]; q+=lsq[g][threadIdx.x]; }
    atomicAdd(&sum0[threadIdx.x], s);
    atomicAdd(&sq0[threadIdx.x], q);
  }
}

// ---------------- fold BN stats -> (a,c) (proven) ----------------
__global__ void k_fold(const float* __restrict__ sum, const float* __restrict__ sq,
                       const float* __restrict__ g, const float* __restrict__ b,
                       float* __restrict__ a, float* __restrict__ c, int C){
  int i = blockIdx.x*64 + threadIdx.x;
  if(i < C){
    float m = sum[i]*(1.0f/NPTS);
    float v = sq[i]*(1.0f/NPTS) - m*m;
    v = fmaxf(v, 0.0f);
    float ai = g[i] / sqrtf(v + EPSV);
    a[i] = ai;
    c[i] = b[i] - m*ai;
  }
}

// ---------------- stats1 (scalar, proven) ----------------
__global__ __launch_bounds__(256) void k_stats1(const float* __restrict__ pts,
    const u32* __restrict__ lin, const u32* __restrict__ counts,
    const float* __restrict__ vsum,
    const float* __restrict__ a0, const float* __restrict__ c0,
    const float* __restrict__ W1, float* __restrict__ sum1, float* __restrict__ sq1){
  __shared__ float ws[4][64], wq[4][64];
  int t = threadIdx.x;
  int p = blockIdx.x*256 + t;
  float f[8]; u32 v;
  point_feats(p, pts, lin, counts, vsum, f, &v);
  float y0[8];
  #pragma unroll
  for(int k=0;k<8;k++) y0[k] = a0[k]*f[k] + c0[k];
  float z[64];
  #pragma unroll
  for(int j=0;j<64;j++){
    float s=0.f;
    #pragma unroll
    for(int k=0;k<8;k++) s += y0[k]*W1[k*64+j];
    z[j]=s;
  }
  int lane = t&63, wv = t>>6;
  float ks=0.f, kq=0.f;
  #pragma unroll
  for(int c=0;c<64;c++){
    float s=z[c], q=z[c]*z[c];
    #pragma unroll
    for(int d=1; d<64; d<<=1){ s+=__shfl_xor(s,d); q+=__shfl_xor(q,d); }
    if(lane==c){ ks=s; kq=q; }
  }
  ws[wv][lane]=ks; wq[wv][lane]=kq;
  __syncthreads();
  if(t<64){
    float S=ws[0][t]+ws[1][t]+ws[2][t]+ws[3][t];
    float Q=wq[0][t]+wq[1][t]+wq[2][t]+wq[3][t];
    atomicAdd(&sum1[t],S); atomicAdd(&sq1[t],Q);
  }
}

// ---------------- mstats2: z2 stats via MFMA (proven) ----------
__global__ __launch_bounds__(256,2) void k_mstats2(
    const float* __restrict__ pts, const u32* __restrict__ lin,
    const u32* __restrict__ counts, const float* __restrict__ vsum,
    const float* __restrict__ a0, const float* __restrict__ c0,
    const float* __restrict__ a1, const float* __restrict__ c1,
    const float* __restrict__ W1, const u16* __restrict__ W2t,
    float* __restrict__ sum2, float* __restrict__ sq2){
  __shared__ u16 T1[256*72];
  int tid = threadIdx.x, lane = tid&63, wid = tid>>6, l15 = lane&15, lg = lane>>4;
  float s2[2] = {0.f,0.f}, q2[2] = {0.f,0.f};

  for(int cch=0; cch<4; cch++){
    int p = blockIdx.x*1024 + cch*256 + tid;
    float f[8]; u32 v;
    point_feats(p, pts, lin, counts, vsum, f, &v);
    float y0[8];
    #pragma unroll
    for(int k=0;k<8;k++) y0[k] = a0[k]*f[k] + c0[k];
    u32 pk[32];
    #pragma unroll
    for(int jj=0;jj<32;jj++){
      float s0=0.f, s1=0.f;
      #pragma unroll
      for(int k=0;k<8;k++){ s0 += y0[k]*W1[k*64+2*jj]; s1 += y0[k]*W1[k*64+2*jj+1]; }
      float v0f = fmaxf(a1[2*jj]*s0   + c1[2*jj],   0.f);
      float v1f = fmaxf(a1[2*jj+1]*s1 + c1[2*jj+1], 0.f);
      pk[jj] = (u32)f2bf(v0f) | ((u32)f2bf(v1f)<<16);
    }
    __syncthreads();
    {
      uint4* dst = (uint4*)&T1[tid*72];
      #pragma unroll
      for(int q=0;q<8;q++) dst[q] = make_uint4(pk[4*q],pk[4*q+1],pk[4*q+2],pk[4*q+3]);
    }
    __syncthreads();
    #pragma unroll
    for(int ci=0; ci<2; ci++){
      int ch = (wid + 4*ci)*16 + l15;
      const u16* wb = W2t + (size_t)ch*64 + lg*8;
      bf16x8 b0 = *(const bf16x8*)(wb);
      bf16x8 b1 = *(const bf16x8*)(wb + 32);
      for(int rt=0; rt<16; rt++){
        const u16* ap = T1 + (rt*16 + l15)*72 + lg*8;
        bf16x8 af0 = *(const bf16x8*)(ap);
        bf16x8 af1 = *(const bf16x8*)(ap + 32);
        f32x4 acc = {0.f,0.f,0.f,0.f};
        acc = __builtin_amdgcn_mfma_f32_16x16x32_bf16(af0, b0, acc, 0,0,0);
        acc = __builtin_amdgcn_mfma_f32_16x16x32_bf16(af1, b1, acc, 0,0,0);
        #pragma unroll
        for(int i=0;i<4;i++){ s2[ci] += acc[i]; q2[ci] += acc[i]*acc[i]; }
      }
    }
  }
  #pragma unroll
  for(int ci=0; ci<2; ci++){
    float s = s2[ci], q = q2[ci];
    s += __shfl_xor(s,16); s += __shfl_xor(s,32);
    q += __shfl_xor(q,16); q += __shfl_xor(q,32);
    if(lg == 0){
      int ch = (wid + 4*ci)*16 + l15;
      atomicAdd(&sum2[ch], s);
      atomicAdd(&sq2[ch], q);
    }
  }
}

// ---------------- chain2: sorted-order chain, z3 stats + y2s dump (proven) -------
__global__ __launch_bounds__(256,1) void k_chain2(
    const float* __restrict__ pts, const u32* __restrict__ lin,
    const u32* __restrict__ counts, const float* __restrict__ vsum,
    const u32* __restrict__ order,
    const float* __restrict__ a0, const float* __restrict__ c0,
    const float* __restrict__ a1, const float* __restrict__ c1,
    const float* __restrict__ a2, const float* __restrict__ c2,
    const float* __restrict__ W1, const u16* __restrict__ W2t,
    const u16* __restrict__ W3t,
    u32* __restrict__ y2s,
    float* __restrict__ sum3, float* __restrict__ sq3){
  __shared__ u16 T1[256*72];
  __shared__ u16 T2[256*136];
  int tid = threadIdx.x, lane = tid&63, wid = tid>>6, l15 = lane&15, lg = lane>>4;
  float s3[4] = {0.f,0.f,0.f,0.f}, q3[4] = {0.f,0.f,0.f,0.f};

  for(int cch=0; cch<4; cch++){
    int rr = blockIdx.x*1024 + cch*256 + tid;   // sorted row index
    int p = (int)order[rr];
    float f[8]; u32 v;
    point_feats(p, pts, lin, counts, vsum, f, &v);
    float y0[8];
    #pragma unroll
    for(int k=0;k<8;k++) y0[k] = a0[k]*f[k] + c0[k];
    u32 pk[32];
    #pragma unroll
    for(int jj=0;jj<32;jj++){
      float s0=0.f, s1=0.f;
      #pragma unroll
      for(int k=0;k<8;k++){ s0 += y0[k]*W1[k*64+2*jj]; s1 += y0[k]*W1[k*64+2*jj+1]; }
      float v0f = fmaxf(a1[2*jj]*s0   + c1[2*jj],   0.f);
      float v1f = fmaxf(a1[2*jj+1]*s1 + c1[2*jj+1], 0.f);
      pk[jj] = (u32)f2bf(v0f) | ((u32)f2bf(v1f)<<16);
    }
    __syncthreads();
    {
      uint4* dst = (uint4*)&T1[tid*72];
      #pragma unroll
      for(int q=0;q<8;q++) dst[q] = make_uint4(pk[4*q],pk[4*q+1],pk[4*q+2],pk[4*q+3]);
    }
    __syncthreads();
    #pragma unroll
    for(int ci=0; ci<2; ci++){
      int ch = (wid + 4*ci)*16 + l15;
      const u16* wb = W2t + (size_t)ch*64 + lg*8;
      bf16x8 b0 = *(const bf16x8*)(wb);
      bf16x8 b1 = *(const bf16x8*)(wb + 32);
      float a2v = a2[ch], c2v = c2[ch];
      for(int rt=0; rt<16; rt++){
        const u16* ap = T1 + (rt*16 + l15)*72 + lg*8;
        bf16x8 af0 = *(const bf16x8*)(ap);
        bf16x8 af1 = *(const bf16x8*)(ap + 32);
        f32x4 acc = {0.f,0.f,0.f,0.f};
        acc = __builtin_amdgcn_mfma_f32_16x16x32_bf16(af0, b0, acc, 0,0,0);
        acc = __builtin_amdgcn_mfma_f32_16x16x32_bf16(af1, b1, acc, 0,0,0);
        int rbase = rt*16 + lg*4;
        #pragma unroll
        for(int i=0;i<4;i++)
          T2[(rbase+i)*136 + ch] = f2bf(fmaxf(a2v*acc[i] + c2v, 0.f));
      }
    }
    __syncthreads();
    {
      const u32* T2w = (const u32*)T2;
      u32 base = (u32)blockIdx.x*1024u + (u32)cch*256u;
      for(int i=tid; i<256*64; i+=256){
        int row = i>>6, w = i&63;
        y2s[(size_t)(base+row)*64 + w] = T2w[row*68 + w];
      }
    }
    #pragma unroll
    for(int ci=0; ci<4; ci++){
      int ch = (wid + 4*ci)*16 + l15;
      const u16* wb = W3t + (size_t)ch*128 + lg*8;
      bf16x8 b[4];
      #pragma unroll
      for(int ks=0; ks<4; ks++) b[ks] = *(const bf16x8*)(wb + ks*32);
      for(int rt=0; rt<16; rt++){
        const u16* ap = T2 + (rt*16 + l15)*136 + lg*8;
        f32x4 acc = {0.f,0.f,0.f,0.f};
        #pragma unroll
        for(int ks=0; ks<4; ks++){
          bf16x8 af = *(const bf16x8*)(ap + ks*32);
          acc = __builtin_amdgcn_mfma_f32_16x16x32_bf16(af, b[ks], acc, 0,0,0);
        }
        #pragma unroll
        for(int i=0;i<4;i++){ s3[ci] += acc[i]; q3[ci] += acc[i]*acc[i]; }
      }
    }
  }
  #pragma unroll
  for(int ci=0; ci<4; ci++){
    float s = s3[ci], q = q3[ci];
    s += __shfl_xor(s,16); s += __shfl_xor(s,32);
    q += __shfl_xor(q,16); q += __shfl_xor(q,32);
    if(lg == 0){
      int ch = (wid + 4*ci)*16 + l15;
      atomicAdd(&sum3[ch], s);
      atomicAdd(&sq3[ch], q);
    }
  }
}

// ---------------- mega5: mega4 dataflow, 512 threads (16 waves/CU) --------------
// Same LDS layout/math as proven mega4; work split across 8 waves:
// L3: 2 ci-tiles/wave; L4+comp: (cg = wid&3) ch-group x (rh = wid>>2) row-half.
__global__ __launch_bounds__(512,4) void k_mega5(
    const u32* __restrict__ offsets, const u32* __restrict__ y2s,
    const float* __restrict__ a3, const float* __restrict__ c3,
    const u16* __restrict__ W3t, const u16* __restrict__ W4t,
    const u16* __restrict__ Wct,
    const float* __restrict__ b4, const float* __restrict__ bc,
    u16* __restrict__ comp){
  __shared__ __align__(16) char SM[65664];
  u16* T3  = (u16*)(SM);            // [80][264]
  u16* T2s = (u16*)(SM + 42240);    // [80][136]  (overlays Tz+TA)
  u16* Tz  = (u16*)(SM + 42240);    // [80][72]
  u16* TA  = (u16*)(SM + 53760);    // [80][72]
  u32* vst = (u32*)(SM + 65280);    // [VCAP+1]
  u32* hdr = (u32*)(SM + 65616);    // [4]

  int tid = threadIdx.x, lane = tid & 63, wid = tid >> 6;   // wid in [0,8)
  int l15 = lane & 15, lg = lane >> 4;
  int cg = wid & 3, rh = wid >> 2;
  int nvt = rh ? 2 : 3, vt0 = rh ? 3 : 0;

  if(tid == 0){
    u32 t0 = (u32)blockIdx.x * 64u;
    u32 lo=0, hi=SS;
    while(lo<hi){ u32 mid=(lo+hi)>>1; if(offsets[mid] < t0) lo=mid+1; else hi=mid; }
    u32 vlo = lo, vhi;
    if(blockIdx.x == NB-1) vhi = SS;
    else {
      u32 t1 = t0 + 64u;
      lo = vlo; hi = SS;
      while(lo<hi){ u32 mid=(lo+hi)>>1; if(offsets[mid] < t1) lo=mid+1; else hi=mid; }
      vhi = lo;
    }
    hdr[0]=vlo; hdr[1]=vhi; hdr[2]=offsets[vlo]; hdr[3]=offsets[vhi];
  }
  __syncthreads();
  u32 vlo=hdr[0], vhi=hdr[1], start=hdr[2], end=hdr[3];
  int R = (int)(end - start); if(R > RCAP) R = RCAP;
  int V = (int)(vhi - vlo);   if(V > VCAP) V = VCAP;

  if(tid <= VCAP){
    u32 o = (tid <= V) ? offsets[vlo + tid] : end;
    int s = (int)(o - start); if(s > RCAP) s = RCAP;
    vst[tid] = (u32)s;
  }

  // ---- stage y2s rows -> T2s (zero pad rows >= R) ----
  {
    u32* T2w = (u32*)T2s;
    for(int i=tid; i<RCAP*64; i+=512){
      int row = i>>6, w = i&63;
      u32 val = (row < R) ? y2s[(size_t)(start+row)*64 + w] : 0u;
      T2w[row*68 + w] = val;
    }
  }
  __syncthreads();

  // ---- L3: T2s(80x128) @ W3t -> bn3relu -> T3(80x256); 2 tiles/wave ----
  for(int ci=0; ci<2; ci++){
    int ch = (wid + 8*ci)*16 + l15;
    const u16* wb = W3t + (size_t)ch*128 + lg*8;
    bf16x8 b[4];
    #pragma unroll
    for(int ks=0; ks<4; ks++) b[ks] = *(const bf16x8*)(wb + ks*32);
    float a3v = a3[ch], c3v = c3[ch];
    for(int rt=0; rt<5; rt++){
      const u16* ap = T2s + (rt*16 + l15)*136 + lg*8;
      f32x4 acc = {0.f,0.f,0.f,0.f};
      #pragma unroll
      for(int ks=0; ks<4; ks++){
        bf16x8 af = *(const bf16x8*)(ap + ks*32);
        acc = __builtin_amdgcn_mfma_f32_16x16x32_bf16(af, b[ks], acc, 0,0,0);
      }
      int rbase = rt*16 + lg*4;
      #pragma unroll
      for(int i=0;i<4;i++)
        T3[(rbase+i)*264 + ch] = f2bf(fmaxf(a3v*acc[i] + c3v, 0.f));
    }
  }
  __syncthreads();

  f32x4 acc3[3];
  #pragma unroll
  for(int i=0;i<3;i++) acc3[i] = (f32x4){0.f,0.f,0.f,0.f};
  int ch4 = cg*16 + l15;   // channel within 64-chunk (both row-halves cover same cg)

  for(int oc=0; oc<4; oc++){
    // z4 chunk -> Tz; wave (cg, rh): ch-tile cg, rows rh0: rt{0,1,2}, rh1: rt{3,4}
    {
      int chg = oc*64 + ch4;
      const u16* wb = W4t + (size_t)chg*256 + lg*8;
      bf16x8 b[8];
      #pragma unroll
      for(int ks=0; ks<8; ks++) b[ks] = *(const bf16x8*)(wb + ks*32);
      int rtB = rh ? 3 : 0, rtE = rh ? 5 : 3;
      for(int rt=rtB; rt<rtE; rt++){
        const u16* ap = T3 + (rt*16 + l15)*264 + lg*8;
        f32x4 acc = {0.f,0.f,0.f,0.f};
        #pragma unroll
        for(int ks=0; ks<8; ks++){
          bf16x8 af = *(const bf16x8*)(ap + ks*32);
          acc = __builtin_amdgcn_mfma_f32_16x16x32_bf16(af, b[ks], acc, 0,0,0);
        }
        int rbase = rt*16 + lg*4;
        #pragma unroll
        for(int i=0;i<4;i++)
          Tz[(rbase+i)*72 + ch4] = f2bf(acc[i]);
      }
    }
    __syncthreads();
    // sorted-segment max (bf16 RNE monotone)
    for(int i=tid; i<VCAP*64; i+=512){
      int v = i>>6, k = i&63;
      u32 r0 = vst[v], r1 = vst[v+1];
      u16 outv = 0;
      if(r1 > r0){
        float m = -3.0e38f;
        for(u32 r=r0; r<r1; r++) m = fmaxf(m, bf2f(Tz[r*72+k]));
        outv = f2bf(m + b4[oc*64+k]);
      }
      TA[v*72+k] = outv;
    }
    __syncthreads();
    // comp partial: TA(80x64) @ Wct[:, oc-chunk]; wave handles its vt subset
    {
      const u16* wb = Wct + (size_t)ch4*256 + oc*64 + lg*8;
      bf16x8 b0 = *(const bf16x8*)(wb);
      bf16x8 b1 = *(const bf16x8*)(wb + 32);
      #pragma unroll
      for(int s=0; s<3; s++){
        if(s < nvt){
          int vt = vt0 + s;
          const u16* ap = TA + (vt*16 + l15)*72 + lg*8;
          bf16x8 af0 = *(const bf16x8*)(ap);
          bf16x8 af1 = *(const bf16x8*)(ap + 32);
          acc3[s] = __builtin_amdgcn_mfma_f32_16x16x32_bf16(af0, b0, acc3[s], 0,0,0);
          acc3[s] = __builtin_amdgcn_mfma_f32_16x16x32_bf16(af1, b1, acc3[s], 0,0,0);
        }
      }
    }
    // no tail barrier: next z4 writes Tz (disjoint from TA); top barrier guards Tz
  }

  // ---- comp write ----
  {
    float bcv = bc[ch4];
    #pragma unroll
    for(int s=0; s<3; s++){
      if(s < nvt){
        int vt = vt0 + s;
        int vbase = vt*16 + lg*4;
        #pragma unroll
        for(int i=0;i<4;i++){
          int vox = vbase + i;
          if(vox < V){
            bool nz = vst[vox+1] > vst[vox];
            float val = nz ? fmaxf(acc3[s][i] + bcv, 0.f) : 0.f;
            comp[(size_t)(vlo+vox)*64 + ch4] = f2bf(val);
          }
        }
      }
    }
  }
}

// ---------------- residual image from comp (proven) ----------------
__global__ __launch_bounds__(256) void k_resid(const u16* __restrict__ comp,
                                               float* __restrict__ out){
  __shared__ u32 cl[4*128*32];
  int t = threadIdx.x;
  int blk = blockIdx.x;
  int wq = blk & 3, h = (blk>>2) & 63, b = blk>>8;
  int w0 = wq*128;
  for(int fr=0; fr<4; fr++){
    const u32* src = (const u32*)comp + ((size_t)(((b*4+fr)*64 + h)*512 + w0))*32;
    for(int i=t; i<4096; i+=256){
      int vox = i>>5, wd = i&31;
      cl[fr*4096 + vox*32 + (wd ^ (vox&31))] = src[i];
    }
  }
  __syncthreads();
  int wl = t & 127, half = t >> 7;
  int mv = wl & 31;
  for(int ch = half; ch < 64; ch += 2){
    u32 wr3 = cl[3*4096 + wl*32 + ((ch>>1) ^ mv)];
    float r3 = bf2f((ch&1) ? (u16)(wr3>>16) : (u16)(wr3&0xFFFFu));
    #pragma unroll
    for(int fr=0; fr<3; fr++){
      u32 wrf = cl[fr*4096 + wl*32 + ((ch>>1) ^ mv)];
      float vf = bf2f((ch&1) ? (u16)(wrf>>16) : (u16)(wrf&0xFFFFu));
      out[(((size_t)(b*192 + fr*64 + ch))*64 + h)*512 + w0 + wl] = r3 - vf;
    }
  }
}

// ------------------------------- launcher -------------------------------------
extern "C" void kernel_launch(void* const* d_in, const int* in_sizes, int n_in,
                              void* d_out, int out_size, void* d_ws, size_t ws_size,
                              hipStream_t stream){
  const float* pts  = (const float*)d_in[0];
  const int*  coors = (const int*)d_in[1];
  const float* g0 = (const float*)d_in[2];
  const float* b0 = (const float*)d_in[3];
  const float* W1 = (const float*)d_in[4];
  const float* g1 = (const float*)d_in[5];
  const float* b1 = (const float*)d_in[6];
  const float* W2 = (const float*)d_in[7];
  const float* g2 = (const float*)d_in[8];
  const float* b2 = (const float*)d_in[9];
  const float* W3 = (const float*)d_in[10];
  const float* g3 = (const float*)d_in[11];
  const float* b3 = (const float*)d_in[12];
  const float* W4 = (const float*)d_in[13];
  const float* b4 = (const float*)d_in[14];
  const float* Wc = (const float*)d_in[15];
  const float* bc = (const float*)d_in[16];
  float* out = (float*)d_out;
  (void)in_sizes; (void)n_in; (void)out_size; (void)ws_size;

  char* ws = (char*)d_ws;
  size_t off = 0;
  auto alloc = [&](size_t bytes)->void*{
    void* p = ws + off;
    off += (bytes + 255) & ~(size_t)255;
    return p;
  };
  u32*  counts  = (u32*)alloc((size_t)SS*4);
  float* vsum   = (float*)alloc((size_t)SS*3*4);
  float* stats  = (float*)alloc(8192);
  size_t zero_bytes = off;
  u32*  lin     = (u32*)alloc((size_t)NPTS*4);
  u32*  offsets = (u32*)alloc((size_t)(SS+1)*4);
  u32*  cursor  = (u32*)alloc((size_t)SS*4);
  u32*  order   = (u32*)alloc((size_t)NPTS*4);
  u32*  blockSums = (u32*)alloc(1024);
  u16*  comp    = (u16*)alloc((size_t)SS*64*2);
  u16*  W2t = (u16*)alloc(8192*2);
  u16*  W3t = (u16*)alloc(32768*2);
  u16*  W4t = (u16*)alloc(65536*2);
  u16*  Wct = (u16*)alloc(16384*2);
  u32*  y2s = (u32*)alloc((size_t)NPTS*64*4);   // 134 MB (proven budget)

  float* sum0=stats+0,   *sq0=stats+8,    *a0=stats+16,   *c0=stats+24;
  float* sum1=stats+32,  *sq1=stats+96,   *a1=stats+160,  *c1=stats+224;
  float* sum2=stats+288, *sq2=stats+416,  *a2=stats+544,  *c2=stats+672;
  float* sum3=stats+800, *sq3=stats+1056, *a3=stats+1312, *c3=stats+1568;

  hipMemsetAsync(d_ws, 0, zero_bytes, stream);

  k_prep   <<<480, 256,0,stream>>>(W2, W3, W4, Wc, W2t, W3t, W4t, Wct);
  k_lin    <<<2048,256,0,stream>>>(pts, coors, lin, counts, vsum);
  k_scan_a <<<256, 256,0,stream>>>(counts, blockSums);
  k_scan_b <<<1,   64, 0,stream>>>(blockSums);
  k_scan_c <<<256, 256,0,stream>>>(counts, blockSums, offsets, cursor);
  k_scatter<<<2048,256,0,stream>>>(lin, cursor, order);

  k_stats0 <<<2048,256,0,stream>>>(pts, lin, counts, vsum, sum0, sq0);
  k_fold   <<<1,   64, 0,stream>>>(sum0, sq0, g0, b0, a0, c0, 8);
  k_stats1 <<<2048,256,0,stream>>>(pts, lin, counts, vsum, a0, c0, W1, sum1, sq1);
  k_fold   <<<1,   64, 0,stream>>>(sum1, sq1, g1, b1, a1, c1, 64);
  k_mstats2<<<512, 256,0,stream>>>(pts, lin, counts, vsum, a0,c0,a1,c1, W1, W2t, sum2, sq2);
  k_fold   <<<2,   64, 0,stream>>>(sum2, sq2, g2, b2, a2, c2, 128);
  k_chain2 <<<512, 256,0,stream>>>(pts, lin, counts, vsum, order,
                                   a0,c0,a1,c1,a2,c2, W1, W2t, W3t,
                                   y2s, sum3, sq3);
  k_fold   <<<4,   64, 0,stream>>>(sum3, sq3, g3, b3, a3, c3, 256);

  k_mega5  <<<NB,  512,0,stream>>>(offsets, y2s, a3,c3, W3t, W4t, Wct, b4, bc, comp);
  k_resid  <<<512, 256,0,stream>>>(comp, out);
}

// Round 12
// 1091.871 us; speedup vs baseline: 1.7355x; 1.0125x over previous
//
#include <hip/hip_runtime.h>
#include <hip/hip_bf16.h>
#include <stdint.h>

typedef unsigned int u32;
typedef unsigned short u16;
typedef __attribute__((ext_vector_type(8))) short bf16x8;
typedef __attribute__((ext_vector_type(4))) float f32x4;

#define NPTS 524288
#define FF 4
#define HH 64
#define WW 512
#define SS 262144
#define EPSV 1e-5f
#define NB 8192      // 64 points per block (mega6)
#define RCAP 80
#define VCAP 80

__device__ __forceinline__ float bf2f(u16 h){ return __uint_as_float(((u32)h)<<16); }
__device__ __forceinline__ u16 f2bf(float f){
  u32 u = __float_as_uint(f);
  return (u16)((u + 0x7FFFu + ((u>>16)&1u)) >> 16);   // RNE (monotone)
}

__device__ __forceinline__ void point_feats(int p, const float* __restrict__ pts,
    const u32* __restrict__ lin, const u32* __restrict__ counts,
    const float* __restrict__ vsum, float f[8], u32* vout){
  float4 pt = ((const float4*)pts)[p];
  u32 v = lin[p];
  float cnt = fmaxf((float)counts[v], 1.0f);
  float inv = 1.0f/cnt;
  float mx = vsum[v*3+0]*inv, my = vsum[v*3+1]*inv, mz = vsum[v*3+2]*inv;
  float dist = sqrtf(pt.x*pt.x + pt.y*pt.y + pt.z*pt.z);
  f[0]=pt.x; f[1]=pt.y; f[2]=pt.z; f[3]=pt.w; f[4]=dist;
  f[5]=pt.x-mx; f[6]=pt.y-my; f[7]=pt.z-mz;
  *vout = v;
}

// ---------------- pass 1: linear voxel id + counts + coord sums ----------------
__global__ __launch_bounds__(256) void k_lin(const float* __restrict__ pts,
                                             const int* __restrict__ coors,
                                             u32* __restrict__ lin,
                                             u32* __restrict__ counts,
                                             float* __restrict__ vsum){
  int p = blockIdx.x*256 + threadIdx.x;
  int4 c = ((const int4*)coors)[p];
  u32 v = ((u32)((c.x*FF + c.y)*HH + c.z))*WW + (u32)c.w;
  lin[p] = v;
  atomicAdd(&counts[v], 1u);
  float4 pt = ((const float4*)pts)[p];
  atomicAdd(&vsum[v*3+0], pt.x);
  atomicAdd(&vsum[v*3+1], pt.y);
  atomicAdd(&vsum[v*3+2], pt.z);
}

// ---------------- counting-sort scan ----------------
__global__ __launch_bounds__(256) void k_scan_a(const u32* __restrict__ counts,
                                                u32* __restrict__ blockSums){
  __shared__ u32 lds[256];
  int b = blockIdx.x, t = threadIdx.x;
  uint4 c4 = ((const uint4*)counts)[b*256 + t];
  lds[t] = c4.x + c4.y + c4.z + c4.w;
  __syncthreads();
  for(int s=128; s>0; s>>=1){ if(t<s) lds[t] += lds[t+s]; __syncthreads(); }
  if(t==0) blockSums[b] = lds[0];
}

__global__ void k_scan_b(u32* blockSums){
  if(threadIdx.x==0){
    u32 run = 0;
    for(int i=0;i<256;i++){ u32 v = blockSums[i]; blockSums[i] = run; run += v; }
  }
}

__global__ __launch_bounds__(256) void k_scan_c(const u32* __restrict__ counts,
                                                const u32* __restrict__ blockSums,
                                                u32* __restrict__ offsets,
                                                u32* __restrict__ cursor){
  __shared__ u32 lds[256];
  int b = blockIdx.x, t = threadIdx.x;
  uint4 c4 = ((const uint4*)counts)[b*256 + t];
  u32 mysum = c4.x + c4.y + c4.z + c4.w;
  lds[t] = mysum;
  __syncthreads();
  for(int d=1; d<256; d<<=1){
    u32 v = (t>=d) ? lds[t-d] : 0u;
    __syncthreads();
    lds[t] += v;
    __syncthreads();
  }
  u32 off = blockSums[b] + (t>0 ? lds[t-1] : 0u);
  u32 base = (u32)(b*1024 + t*4);
  offsets[base+0]=off; cursor[base+0]=off; off += c4.x;
  offsets[base+1]=off; cursor[base+1]=off; off += c4.y;
  offsets[base+2]=off; cursor[base+2]=off; off += c4.z;
  offsets[base+3]=off; cursor[base+3]=off; off += c4.w;
  if(base+4 == SS) offsets[SS] = off;
}

__global__ __launch_bounds__(256) void k_scatter(const u32* __restrict__ lin,
                                                 u32* __restrict__ cursor,
                                                 u32* __restrict__ order){
  int p = blockIdx.x*256 + threadIdx.x;
  u32 v = lin[p];
  u32 pos = atomicAdd(&cursor[v], 1u);
  order[pos] = p;
}

// ---------------- weight prep: bf16 transposed ----------------
__global__ __launch_bounds__(256) void k_prep(const float* __restrict__ W2,
    const float* __restrict__ W3, const float* __restrict__ W4,
    const float* __restrict__ Wc,
    u16* __restrict__ W2t, u16* __restrict__ W3t, u16* __restrict__ W4t,
    u16* __restrict__ Wct){
  int i = blockIdx.x*256 + threadIdx.x;
  if(i < 8192){
    int k = i >> 7, n = i & 127;
    W2t[n*64 + k] = f2bf(W2[i]);
  } else if(i < 8192+32768){
    int j = i - 8192;
    int k = j >> 8, n = j & 255;
    W3t[n*128 + k] = f2bf(W3[j]);
  } else if(i < 8192+32768+65536){
    int j = i - (8192+32768);
    int k = j >> 8, n = j & 255;
    W4t[n*256 + k] = f2bf(W4[j]);
  } else if(i < 8192+32768+65536+16384){
    int j = i - (8192+32768+65536);
    int k = j >> 6, n = j & 63;
    Wct[n*256 + k] = f2bf(Wc[j]);
  }
}

// ---------------- stats0 (proven) ----------------
__global__ __launch_bounds__(256) void k_stats0(const float* __restrict__ pts,
    const u32* __restrict__ lin, const u32* __restrict__ counts,
    const float* __restrict__ vsum, float* __restrict__ sum0, float* __restrict__ sq0){
  int p = blockIdx.x*256 + threadIdx.x;
  float f[8]; u32 v;
  point_feats(p, pts, lin, counts, vsum, f, &v);
  __shared__ float lsum[4][8], lsq[4][8];
  int lane = threadIdx.x & 63, wv = threadIdx.x >> 6;
  #pragma unroll
  for(int c=0;c<8;c++){
    float s = f[c], q = f[c]*f[c];
    #pragma unroll
    for(int d=32; d; d>>=1){ s += __shfl_xor(s,d); q += __shfl_xor(q,d); }
    if(lane==0){ lsum[wv][c]=s; lsq[wv][c]=q; }
  }
  __syncthreads();
  if(threadIdx.x<8){
    float s=0.f,q=0.f;
    for(int g=0;g<4;g++){ s+=lsum[g][threadIdx.x]; q+=lsq[g][threadIdx.x]; }
    atomicAdd(&sum0[threadIdx.x], s);
    atomicAdd(&sq0[threadIdx.x], q);
  }
}

// ---------------- fold BN stats -> (a,c) (proven) ----------------
__global__ void k_fold(const float* __restrict__ sum, const float* __restrict__ sq,
                       const float* __restrict__ g, const float* __restrict__ b,
                       float* __restrict__ a, float* __restrict__ c, int C){
  int i = blockIdx.x*64 + threadIdx.x;
  if(i < C){
    float m = sum[i]*(1.0f/NPTS);
    float v = sq[i]*(1.0f/NPTS) - m*m;
    v = fmaxf(v, 0.0f);
    float ai = g[i] / sqrtf(v + EPSV);
    a[i] = ai;
    c[i] = b[i] - m*ai;
  }
}

// ---------------- stats1 (scalar, proven) ----------------
__global__ __launch_bounds__(256) void k_stats1(const float* __restrict__ pts,
    const u32* __restrict__ lin, const u32* __restrict__ counts,
    const float* __restrict__ vsum,
    const float* __restrict__ a0, const float* __restrict__ c0,
    const float* __restrict__ W1, float* __restrict__ sum1, float* __restrict__ sq1){
  __shared__ float ws[4][64], wq[4][64];
  int t = threadIdx.x;
  int p = blockIdx.x*256 + t;
  float f[8]; u32 v;
  point_feats(p, pts, lin, counts, vsum, f, &v);
  float y0[8];
  #pragma unroll
  for(int k=0;k<8;k++) y0[k] = a0[k]*f[k] + c0[k];
  float z[64];
  #pragma unroll
  for(int j=0;j<64;j++){
    float s=0.f;
    #pragma unroll
    for(int k=0;k<8;k++) s += y0[k]*W1[k*64+j];
    z[j]=s;
  }
  int lane = t&63, wv = t>>6;
  float ks=0.f, kq=0.f;
  #pragma unroll
  for(int c=0;c<64;c++){
    float s=z[c], q=z[c]*z[c];
    #pragma unroll
    for(int d=1; d<64; d<<=1){ s+=__shfl_xor(s,d); q+=__shfl_xor(q,d); }
    if(lane==c){ ks=s; kq=q; }
  }
  ws[wv][lane]=ks; wq[wv][lane]=kq;
  __syncthreads();
  if(t<64){
    float S=ws[0][t]+ws[1][t]+ws[2][t]+ws[3][t];
    float Q=wq[0][t]+wq[1][t]+wq[2][t]+wq[3][t];
    atomicAdd(&sum1[t],S); atomicAdd(&sq1[t],Q);
  }
}

// ---------------- mstats2: z2 stats via MFMA (proven) ----------
__global__ __launch_bounds__(256,2) void k_mstats2(
    const float* __restrict__ pts, const u32* __restrict__ lin,
    const u32* __restrict__ counts, const float* __restrict__ vsum,
    const float* __restrict__ a0, const float* __restrict__ c0,
    const float* __restrict__ a1, const float* __restrict__ c1,
    const float* __restrict__ W1, const u16* __restrict__ W2t,
    float* __restrict__ sum2, float* __restrict__ sq2){
  __shared__ u16 T1[256*72];
  int tid = threadIdx.x, lane = tid&63, wid = tid>>6, l15 = lane&15, lg = lane>>4;
  float s2[2] = {0.f,0.f}, q2[2] = {0.f,0.f};

  for(int cch=0; cch<4; cch++){
    int p = blockIdx.x*1024 + cch*256 + tid;
    float f[8]; u32 v;
    point_feats(p, pts, lin, counts, vsum, f, &v);
    float y0[8];
    #pragma unroll
    for(int k=0;k<8;k++) y0[k] = a0[k]*f[k] + c0[k];
    u32 pk[32];
    #pragma unroll
    for(int jj=0;jj<32;jj++){
      float s0=0.f, s1=0.f;
      #pragma unroll
      for(int k=0;k<8;k++){ s0 += y0[k]*W1[k*64+2*jj]; s1 += y0[k]*W1[k*64+2*jj+1]; }
      float v0f = fmaxf(a1[2*jj]*s0   + c1[2*jj],   0.f);
      float v1f = fmaxf(a1[2*jj+1]*s1 + c1[2*jj+1], 0.f);
      pk[jj] = (u32)f2bf(v0f) | ((u32)f2bf(v1f)<<16);
    }
    __syncthreads();
    {
      uint4* dst = (uint4*)&T1[tid*72];
      #pragma unroll
      for(int q=0;q<8;q++) dst[q] = make_uint4(pk[4*q],pk[4*q+1],pk[4*q+2],pk[4*q+3]);
    }
    __syncthreads();
    #pragma unroll
    for(int ci=0; ci<2; ci++){
      int ch = (wid + 4*ci)*16 + l15;
      const u16* wb = W2t + (size_t)ch*64 + lg*8;
      bf16x8 b0 = *(const bf16x8*)(wb);
      bf16x8 b1 = *(const bf16x8*)(wb + 32);
      for(int rt=0; rt<16; rt++){
        const u16* ap = T1 + (rt*16 + l15)*72 + lg*8;
        bf16x8 af0 = *(const bf16x8*)(ap);
        bf16x8 af1 = *(const bf16x8*)(ap + 32);
        f32x4 acc = {0.f,0.f,0.f,0.f};
        acc = __builtin_amdgcn_mfma_f32_16x16x32_bf16(af0, b0, acc, 0,0,0);
        acc = __builtin_amdgcn_mfma_f32_16x16x32_bf16(af1, b1, acc, 0,0,0);
        #pragma unroll
        for(int i=0;i<4;i++){ s2[ci] += acc[i]; q2[ci] += acc[i]*acc[i]; }
      }
    }
  }
  #pragma unroll
  for(int ci=0; ci<2; ci++){
    float s = s2[ci], q = q2[ci];
    s += __shfl_xor(s,16); s += __shfl_xor(s,32);
    q += __shfl_xor(q,16); q += __shfl_xor(q,32);
    if(lg == 0){
      int ch = (wid + 4*ci)*16 + l15;
      atomicAdd(&sum2[ch], s);
      atomicAdd(&sq2[ch], q);
    }
  }
}

// ---------------- chain2: sorted-order chain, z3 stats + y2s dump (proven) -------
__global__ __launch_bounds__(256,1) void k_chain2(
    const float* __restrict__ pts, const u32* __restrict__ lin,
    const u32* __restrict__ counts, const float* __restrict__ vsum,
    const u32* __restrict__ order,
    const float* __restrict__ a0, const float* __restrict__ c0,
    const float* __restrict__ a1, const float* __restrict__ c1,
    const float* __restrict__ a2, const float* __restrict__ c2,
    const float* __restrict__ W1, const u16* __restrict__ W2t,
    const u16* __restrict__ W3t,
    u32* __restrict__ y2s,
    float* __restrict__ sum3, float* __restrict__ sq3){
  __shared__ u16 T1[256*72];
  __shared__ u16 T2[256*136];
  int tid = threadIdx.x, lane = tid&63, wid = tid>>6, l15 = lane&15, lg = lane>>4;
  float s3[4] = {0.f,0.f,0.f,0.f}, q3[4] = {0.f,0.f,0.f,0.f};

  for(int cch=0; cch<4; cch++){
    int rr = blockIdx.x*1024 + cch*256 + tid;   // sorted row index
    int p = (int)order[rr];
    float f[8]; u32 v;
    point_feats(p, pts, lin, counts, vsum, f, &v);
    float y0[8];
    #pragma unroll
    for(int k=0;k<8;k++) y0[k] = a0[k]*f[k] + c0[k];
    u32 pk[32];
    #pragma unroll
    for(int jj=0;jj<32;jj++){
      float s0=0.f, s1=0.f;
      #pragma unroll
      for(int k=0;k<8;k++){ s0 += y0[k]*W1[k*64+2*jj]; s1 += y0[k]*W1[k*64+2*jj+1]; }
      float v0f = fmaxf(a1[2*jj]*s0   + c1[2*jj],   0.f);
      float v1f = fmaxf(a1[2*jj+1]*s1 + c1[2*jj+1], 0.f);
      pk[jj] = (u32)f2bf(v0f) | ((u32)f2bf(v1f)<<16);
    }
    __syncthreads();
    {
      uint4* dst = (uint4*)&T1[tid*72];
      #pragma unroll
      for(int q=0;q<8;q++) dst[q] = make_uint4(pk[4*q],pk[4*q+1],pk[4*q+2],pk[4*q+3]);
    }
    __syncthreads();
    #pragma unroll
    for(int ci=0; ci<2; ci++){
      int ch = (wid + 4*ci)*16 + l15;
      const u16* wb = W2t + (size_t)ch*64 + lg*8;
      bf16x8 b0 = *(const bf16x8*)(wb);
      bf16x8 b1 = *(const bf16x8*)(wb + 32);
      float a2v = a2[ch], c2v = c2[ch];
      for(int rt=0; rt<16; rt++){
        const u16* ap = T1 + (rt*16 + l15)*72 + lg*8;
        bf16x8 af0 = *(const bf16x8*)(ap);
        bf16x8 af1 = *(const bf16x8*)(ap + 32);
        f32x4 acc = {0.f,0.f,0.f,0.f};
        acc = __builtin_amdgcn_mfma_f32_16x16x32_bf16(af0, b0, acc, 0,0,0);
        acc = __builtin_amdgcn_mfma_f32_16x16x32_bf16(af1, b1, acc, 0,0,0);
        int rbase = rt*16 + lg*4;
        #pragma unroll
        for(int i=0;i<4;i++)
          T2[(rbase+i)*136 + ch] = f2bf(fmaxf(a2v*acc[i] + c2v, 0.f));
      }
    }
    __syncthreads();
    {
      const u32* T2w = (const u32*)T2;
      u32 base = (u32)blockIdx.x*1024u + (u32)cch*256u;
      for(int i=tid; i<256*64; i+=256){
        int row = i>>6, w = i&63;
        y2s[(size_t)(base+row)*64 + w] = T2w[row*68 + w];
      }
    }
    #pragma unroll
    for(int ci=0; ci<4; ci++){
      int ch = (wid + 4*ci)*16 + l15;
      const u16* wb = W3t + (size_t)ch*128 + lg*8;
      bf16x8 b[4];
      #pragma unroll
      for(int ks=0; ks<4; ks++) b[ks] = *(const bf16x8*)(wb + ks*32);
      for(int rt=0; rt<16; rt++){
        const u16* ap = T2 + (rt*16 + l15)*136 + lg*8;
        f32x4 acc = {0.f,0.f,0.f,0.f};
        #pragma unroll
        for(int ks=0; ks<4; ks++){
          bf16x8 af = *(const bf16x8*)(ap + ks*32);
          acc = __builtin_amdgcn_mfma_f32_16x16x32_bf16(af, b[ks], acc, 0,0,0);
        }
        #pragma unroll
        for(int i=0;i<4;i++){ s3[ci] += acc[i]; q3[ci] += acc[i]*acc[i]; }
      }
    }
  }
  #pragma unroll
  for(int ci=0; ci<4; ci++){
    float s = s3[ci], q = q3[ci];
    s += __shfl_xor(s,16); s += __shfl_xor(s,32);
    q += __shfl_xor(q,16); q += __shfl_xor(q,32);
    if(lg == 0){
      int ch = (wid + 4*ci)*16 + l15;
      atomicAdd(&sum3[ch], s);
      atomicAdd(&sq3[ch], q);
    }
  }
}

// ---------------- mega6: mega5 + oc-pairing (T3 reads halved), f2bf only --------
// 512 threads, 8 waves: L3 2 tiles/wave; L4 pair: wave (cg,rh) computes ch-tile cg
// for BOTH chunks of the pair (A-frag read shared), rows split by rh.
__global__ __launch_bounds__(512,4) void k_mega6(
    const u32* __restrict__ offsets, const u32* __restrict__ y2s,
    const float* __restrict__ a3, const float* __restrict__ c3,
    const u16* __restrict__ W3t, const u16* __restrict__ W4t,
    const u16* __restrict__ Wct,
    const float* __restrict__ b4, const float* __restrict__ bc,
    u16* __restrict__ comp){
  __shared__ __align__(16) char SM[78208];
  u16* T3  = (u16*)(SM);            // [80][264] 42240
  u16* T2s = (u16*)(SM + 42240);    // [80][136] 21760 (staging; dead after L3)
  u16* Tz0 = (u16*)(SM + 42240);    // [80][72] 11520
  u16* Tz1 = (u16*)(SM + 53760);    // [80][72] 11520
  u16* TA  = (u16*)(SM + 65280);    // [80][72] 11520
  u32* vst = (u32*)(SM + 76800);    // [VCAP+1]
  float* bb = (float*)(SM + 77152); // [256] b4 preload
  u32* hdr = (u32*)(SM + 78176);    // [4]

  int tid = threadIdx.x, lane = tid & 63, wid = tid >> 6;   // wid in [0,8)
  int l15 = lane & 15, lg = lane >> 4;
  int cg = wid & 3, rh = wid >> 2;
  int nvt = rh ? 2 : 3, vt0 = rh ? 3 : 0;

  if(tid == 0){
    u32 t0 = (u32)blockIdx.x * 64u;
    u32 lo=0, hi=SS;
    while(lo<hi){ u32 mid=(lo+hi)>>1; if(offsets[mid] < t0) lo=mid+1; else hi=mid; }
    u32 vlo = lo, vhi;
    if(blockIdx.x == NB-1) vhi = SS;
    else {
      u32 t1 = t0 + 64u;
      lo = vlo; hi = SS;
      while(lo<hi){ u32 mid=(lo+hi)>>1; if(offsets[mid] < t1) lo=mid+1; else hi=mid; }
      vhi = lo;
    }
    hdr[0]=vlo; hdr[1]=vhi; hdr[2]=offsets[vlo]; hdr[3]=offsets[vhi];
  }
  if(tid < 256) bb[tid] = b4[tid];
  __syncthreads();
  u32 vlo=hdr[0], vhi=hdr[1], start=hdr[2], end=hdr[3];
  int R = (int)(end - start); if(R > RCAP) R = RCAP;
  int V = (int)(vhi - vlo);   if(V > VCAP) V = VCAP;

  if(tid <= VCAP){
    u32 o = (tid <= V) ? offsets[vlo + tid] : end;
    int s = (int)(o - start); if(s > RCAP) s = RCAP;
    vst[tid] = (u32)s;
  }

  // ---- stage y2s rows -> T2s (zero pad rows >= R) ----
  {
    u32* T2w = (u32*)T2s;
    for(int i=tid; i<RCAP*64; i+=512){
      int row = i>>6, w = i&63;
      u32 val = (row < R) ? y2s[(size_t)(start+row)*64 + w] : 0u;
      T2w[row*68 + w] = val;
    }
  }
  __syncthreads();

  // ---- L3: T2s(80x128) @ W3t -> bn3relu -> T3(80x256); 2 tiles/wave ----
  for(int ci=0; ci<2; ci++){
    int ch = (wid + 8*ci)*16 + l15;
    const u16* wb = W3t + (size_t)ch*128 + lg*8;
    bf16x8 b[4];
    #pragma unroll
    for(int ks=0; ks<4; ks++) b[ks] = *(const bf16x8*)(wb + ks*32);
    float a3v = a3[ch], c3v = c3[ch];
    for(int rt=0; rt<5; rt++){
      const u16* ap = T2s + (rt*16 + l15)*136 + lg*8;
      f32x4 acc = {0.f,0.f,0.f,0.f};
      #pragma unroll
      for(int ks=0; ks<4; ks++){
        bf16x8 af = *(const bf16x8*)(ap + ks*32);
        acc = __builtin_amdgcn_mfma_f32_16x16x32_bf16(af, b[ks], acc, 0,0,0);
      }
      int rbase = rt*16 + lg*4;
      #pragma unroll
      for(int i=0;i<4;i++)
        T3[(rbase+i)*264 + ch] = f2bf(fmaxf(a3v*acc[i] + c3v, 0.f));
    }
  }
  __syncthreads();

  f32x4 acc3[3];
  #pragma unroll
  for(int i=0;i<3;i++) acc3[i] = (f32x4){0.f,0.f,0.f,0.f};
  int ch4 = cg*16 + l15;

  for(int pr=0; pr<2; pr++){
    int oc0 = 2*pr, oc1 = 2*pr + 1;
    // z4 pair: each A-frag read feeds MFMA for BOTH chunks
    {
      const u16* wb0 = W4t + (size_t)(oc0*64 + ch4)*256 + lg*8;
      const u16* wb1 = W4t + (size_t)(oc1*64 + ch4)*256 + lg*8;
      bf16x8 b0[8], b1[8];
      #pragma unroll
      for(int ks=0; ks<8; ks++){
        b0[ks] = *(const bf16x8*)(wb0 + ks*32);
        b1[ks] = *(const bf16x8*)(wb1 + ks*32);
      }
      int rtB = rh ? 3 : 0, rtE = rh ? 5 : 3;
      for(int rt=rtB; rt<rtE; rt++){
        const u16* ap = T3 + (rt*16 + l15)*264 + lg*8;
        f32x4 aA = {0.f,0.f,0.f,0.f}, aB = {0.f,0.f,0.f,0.f};
        #pragma unroll
        for(int ks=0; ks<8; ks++){
          bf16x8 af = *(const bf16x8*)(ap + ks*32);
          aA = __builtin_amdgcn_mfma_f32_16x16x32_bf16(af, b0[ks], aA, 0,0,0);
          aB = __builtin_amdgcn_mfma_f32_16x16x32_bf16(af, b1[ks], aB, 0,0,0);
        }
        int rbase = rt*16 + lg*4;
        #pragma unroll
        for(int i=0;i<4;i++){
          Tz0[(rbase+i)*72 + ch4] = f2bf(aA[i]);
          Tz1[(rbase+i)*72 + ch4] = f2bf(aB[i]);
        }
      }
    }
    __syncthreads();
    // segmax oc0: Tz0 -> TA
    for(int i=tid; i<VCAP*64; i+=512){
      int v = i>>6, k = i&63;
      u32 r0 = vst[v], r1 = vst[v+1];
      u16 outv = 0;
      if(r1 > r0){
        float m = -3.0e38f;
        for(u32 r=r0; r<r1; r++) m = fmaxf(m, bf2f(Tz0[r*72+k]));
        outv = f2bf(m + bb[oc0*64+k]);
      }
      TA[v*72+k] = outv;
    }
    __syncthreads();
    // comp oc0
    {
      const u16* wb = Wct + (size_t)ch4*256 + oc0*64 + lg*8;
      bf16x8 c0f = *(const bf16x8*)(wb);
      bf16x8 c1f = *(const bf16x8*)(wb + 32);
      #pragma unroll
      for(int s=0; s<3; s++){
        if(s < nvt){
          int vt = vt0 + s;
          const u16* ap = TA + (vt*16 + l15)*72 + lg*8;
          bf16x8 af0 = *(const bf16x8*)(ap);
          bf16x8 af1 = *(const bf16x8*)(ap + 32);
          acc3[s] = __builtin_amdgcn_mfma_f32_16x16x32_bf16(af0, c0f, acc3[s], 0,0,0);
          acc3[s] = __builtin_amdgcn_mfma_f32_16x16x32_bf16(af1, c1f, acc3[s], 0,0,0);
        }
      }
    }
    __syncthreads();   // comp0 done reading TA before segmax1 overwrites
    // segmax oc1: Tz1 -> TA
    for(int i=tid; i<VCAP*64; i+=512){
      int v = i>>6, k = i&63;
      u32 r0 = vst[v], r1 = vst[v+1];
      u16 outv = 0;
      if(r1 > r0){
        float m = -3.0e38f;
        for(u32 r=r0; r<r1; r++) m = fmaxf(m, bf2f(Tz1[r*72+k]));
        outv = f2bf(m + bb[oc1*64+k]);
      }
      TA[v*72+k] = outv;
    }
    __syncthreads();
    // comp oc1
    {
      const u16* wb = Wct + (size_t)ch4*256 + oc1*64 + lg*8;
      bf16x8 c0f = *(const bf16x8*)(wb);
      bf16x8 c1f = *(const bf16x8*)(wb + 32);
      #pragma unroll
      for(int s=0; s<3; s++){
        if(s < nvt){
          int vt = vt0 + s;
          const u16* ap = TA + (vt*16 + l15)*72 + lg*8;
          bf16x8 af0 = *(const bf16x8*)(ap);
          bf16x8 af1 = *(const bf16x8*)(ap + 32);
          acc3[s] = __builtin_amdgcn_mfma_f32_16x16x32_bf16(af0, c0f, acc3[s], 0,0,0);
          acc3[s] = __builtin_amdgcn_mfma_f32_16x16x32_bf16(af1, c1f, acc3[s], 0,0,0);
        }
      }
    }
    __syncthreads();   // all TA reads done before next pair's Tz writes + segmax
  }

  // ---- comp write ----
  {
    float bcv = bc[ch4];
    #pragma unroll
    for(int s=0; s<3; s++){
      if(s < nvt){
        int vt = vt0 + s;
        int vbase = vt*16 + lg*4;
        #pragma unroll
        for(int i=0;i<4;i++){
          int vox = vbase + i;
          if(vox < V){
            bool nz = vst[vox+1] > vst[vox];
            float val = nz ? fmaxf(acc3[s][i] + bcv, 0.f) : 0.f;
            comp[(size_t)(vlo+vox)*64 + ch4] = f2bf(val);
          }
        }
      }
    }
  }
}

// ---------------- residual image from comp (proven) ----------------
__global__ __launch_bounds__(256) void k_resid(const u16* __restrict__ comp,
                                               float* __restrict__ out){
  __shared__ u32 cl[4*128*32];
  int t = threadIdx.x;
  int blk = blockIdx.x;
  int wq = blk & 3, h = (blk>>2) & 63, b = blk>>8;
  int w0 = wq*128;
  for(int fr=0; fr<4; fr++){
    const u32* src = (const u32*)comp + ((size_t)(((b*4+fr)*64 + h)*512 + w0))*32;
    for(int i=t; i<4096; i+=256){
      int vox = i>>5, wd = i&31;
      cl[fr*4096 + vox*32 + (wd ^ (vox&31))] = src[i];
    }
  }
  __syncthreads();
  int wl = t & 127, half = t >> 7;
  int mv = wl & 31;
  for(int ch = half; ch < 64; ch += 2){
    u32 wr3 = cl[3*4096 + wl*32 + ((ch>>1) ^ mv)];
    float r3 = bf2f((ch&1) ? (u16)(wr3>>16) : (u16)(wr3&0xFFFFu));
    #pragma unroll
    for(int fr=0; fr<3; fr++){
      u32 wrf = cl[fr*4096 + wl*32 + ((ch>>1) ^ mv)];
      float vf = bf2f((ch&1) ? (u16)(wrf>>16) : (u16)(wrf&0xFFFFu));
      out[(((size_t)(b*192 + fr*64 + ch))*64 + h)*512 + w0 + wl] = r3 - vf;
    }
  }
}

// ------------------------------- launcher -------------------------------------
extern "C" void kernel_launch(void* const* d_in, const int* in_sizes, int n_in,
                              void* d_out, int out_size, void* d_ws, size_t ws_size,
                              hipStream_t stream){
  const float* pts  = (const float*)d_in[0];
  const int*  coors = (const int*)d_in[1];
  const float* g0 = (const float*)d_in[2];
  const float* b0 = (const float*)d_in[3];
  const float* W1 = (const float*)d_in[4];
  const float* g1 = (const float*)d_in[5];
  const float* b1 = (const float*)d_in[6];
  const float* W2 = (const float*)d_in[7];
  const float* g2 = (const float*)d_in[8];
  const float* b2 = (const float*)d_in[9];
  const float* W3 = (const float*)d_in[10];
  const float* g3 = (const float*)d_in[11];
  const float* b3 = (const float*)d_in[12];
  const float* W4 = (const float*)d_in[13];
  const float* b4 = (const float*)d_in[14];
  const float* Wc = (const float*)d_in[15];
  const float* bc = (const float*)d_in[16];
  float* out = (float*)d_out;
  (void)in_sizes; (void)n_in; (void)out_size; (void)ws_size;

  char* ws = (char*)d_ws;
  size_t off = 0;
  auto alloc = [&](size_t bytes)->void*{
    void* p = ws + off;
    off += (bytes + 255) & ~(size_t)255;
    return p;
  };
  u32*  counts  = (u32*)alloc((size_t)SS*4);
  float* vsum   = (float*)alloc((size_t)SS*3*4);
  float* stats  = (float*)alloc(8192);
  size_t zero_bytes = off;
  u32*  lin     = (u32*)alloc((size_t)NPTS*4);
  u32*  offsets = (u32*)alloc((size_t)(SS+1)*4);
  u32*  cursor  = (u32*)alloc((size_t)SS*4);
  u32*  order   = (u32*)alloc((size_t)NPTS*4);
  u32*  blockSums = (u32*)alloc(1024);
  u16*  comp    = (u16*)alloc((size_t)SS*64*2);
  u16*  W2t = (u16*)alloc(8192*2);
  u16*  W3t = (u16*)alloc(32768*2);
  u16*  W4t = (u16*)alloc(65536*2);
  u16*  Wct = (u16*)alloc(16384*2);
  u32*  y2s = (u32*)alloc((size_t)NPTS*64*4);   // 134 MB (proven budget)

  float* sum0=stats+0,   *sq0=stats+8,    *a0=stats+16,   *c0=stats+24;
  float* sum1=stats+32,  *sq1=stats+96,   *a1=stats+160,  *c1=stats+224;
  float* sum2=stats+288, *sq2=stats+416,  *a2=stats+544,  *c2=stats+672;
  float* sum3=stats+800, *sq3=stats+1056, *a3=stats+1312, *c3=stats+1568;

  hipMemsetAsync(d_ws, 0, zero_bytes, stream);

  k_prep   <<<480, 256,0,stream>>>(W2, W3, W4, Wc, W2t, W3t, W4t, Wct);
  k_lin    <<<2048,256,0,stream>>>(pts, coors, lin, counts, vsum);
  k_scan_a <<<256, 256,0,stream>>>(counts, blockSums);
  k_scan_b <<<1,   64, 0,stream>>>(blockSums);
  k_scan_c <<<256, 256,0,stream>>>(counts, blockSums, offsets, cursor);
  k_scatter<<<2048,256,0,stream>>>(lin, cursor, order);

  k_stats0 <<<2048,256,0,stream>>>(pts, lin, counts, vsum, sum0, sq0);
  k_fold   <<<1,   64, 0,stream>>>(sum0, sq0, g0, b0, a0, c0, 8);
  k_stats1 <<<2048,256,0,stream>>>(pts, lin, counts, vsum, a0, c0, W1, sum1, sq1);
  k_fold   <<<1,   64, 0,stream>>>(sum1, sq1, g1, b1, a1, c1, 64);
  k_mstats2<<<512, 256,0,stream>>>(pts, lin, counts, vsum, a0,c0,a1,c1, W1, W2t, sum2, sq2);
  k_fold   <<<2,   64, 0,stream>>>(sum2, sq2, g2, b2, a2, c2, 128);
  k_chain2 <<<512, 256,0,stream>>>(pts, lin, counts, vsum, order,
                                   a0,c0,a1,c1,a2,c2, W1, W2t, W3t,
                                   y2s, sum3, sq3);
  k_fold   <<<4,   64, 0,stream>>>(sum3, sq3, g3, b3, a3, c3, 256);

  k_mega6  <<<NB,  512,0,stream>>>(offsets, y2s, a3,c3, W3t, W4t, Wct, b4, bc, comp);
  k_resid  <<<512, 256,0,stream>>>(comp, out);
}

// Round 13
// 1065.628 us; speedup vs baseline: 1.7782x; 1.0246x over previous
//
#include <hip/hip_runtime.h>
#include <hip/hip_bf16.h>
#include <stdint.h>

typedef unsigned int u32;
typedef unsigned short u16;
typedef __attribute__((ext_vector_type(8))) short bf16x8;
typedef __attribute__((ext_vector_type(4))) float f32x4;

#define NPTS 524288
#define FF 4
#define HH 64
#define WW 512
#define SS 262144
#define EPSV 1e-5f
#define NB 8192
#define RCAP 80
#define VCAP 80

__device__ __forceinline__ float bf2f(u16 h){ return __uint_as_float(((u32)h)<<16); }
__device__ __forceinline__ u16 f2bf(float f){
  u32 u = __float_as_uint(f);
  return (u16)((u + 0x7FFFu + ((u>>16)&1u)) >> 16);   // RNE (monotone)
}

__device__ __forceinline__ void point_feats(int p, const float* __restrict__ pts,
    const u32* __restrict__ lin, const u32* __restrict__ counts,
    const float* __restrict__ vsum, float f[8], u32* vout){
  float4 pt = ((const float4*)pts)[p];
  u32 v = lin[p];
  float cnt = fmaxf((float)counts[v], 1.0f);
  float inv = 1.0f/cnt;
  float mx = vsum[v*3+0]*inv, my = vsum[v*3+1]*inv, mz = vsum[v*3+2]*inv;
  float dist = sqrtf(pt.x*pt.x + pt.y*pt.y + pt.z*pt.z);
  f[0]=pt.x; f[1]=pt.y; f[2]=pt.z; f[3]=pt.w; f[4]=dist;
  f[5]=pt.x-mx; f[6]=pt.y-my; f[7]=pt.z-mz;
  *vout = v;
}

// ---------------- pass 1: linear voxel id + counts + coord sums ----------------
__global__ __launch_bounds__(256) void k_lin(const float* __restrict__ pts,
                                             const int* __restrict__ coors,
                                             u32* __restrict__ lin,
                                             u32* __restrict__ counts,
                                             float* __restrict__ vsum){
  int p = blockIdx.x*256 + threadIdx.x;
  int4 c = ((const int4*)coors)[p];
  u32 v = ((u32)((c.x*FF + c.y)*HH + c.z))*WW + (u32)c.w;
  lin[p] = v;
  atomicAdd(&counts[v], 1u);
  float4 pt = ((const float4*)pts)[p];
  atomicAdd(&vsum[v*3+0], pt.x);
  atomicAdd(&vsum[v*3+1], pt.y);
  atomicAdd(&vsum[v*3+2], pt.z);
}

// ---------------- counting-sort scan ----------------
__global__ __launch_bounds__(256) void k_scan_a(const u32* __restrict__ counts,
                                                u32* __restrict__ blockSums){
  __shared__ u32 lds[256];
  int b = blockIdx.x, t = threadIdx.x;
  uint4 c4 = ((const uint4*)counts)[b*256 + t];
  lds[t] = c4.x + c4.y + c4.z + c4.w;
  __syncthreads();
  for(int s=128; s>0; s>>=1){ if(t<s) lds[t] += lds[t+s]; __syncthreads(); }
  if(t==0) blockSums[b] = lds[0];
}

__global__ void k_scan_b(u32* blockSums){
  if(threadIdx.x==0){
    u32 run = 0;
    for(int i=0;i<256;i++){ u32 v = blockSums[i]; blockSums[i] = run; run += v; }
  }
}

__global__ __launch_bounds__(256) void k_scan_c(const u32* __restrict__ counts,
                                                const u32* __restrict__ blockSums,
                                                u32* __restrict__ offsets,
                                                u32* __restrict__ cursor){
  __shared__ u32 lds[256];
  int b = blockIdx.x, t = threadIdx.x;
  uint4 c4 = ((const uint4*)counts)[b*256 + t];
  u32 mysum = c4.x + c4.y + c4.z + c4.w;
  lds[t] = mysum;
  __syncthreads();
  for(int d=1; d<256; d<<=1){
    u32 v = (t>=d) ? lds[t-d] : 0u;
    __syncthreads();
    lds[t] += v;
    __syncthreads();
  }
  u32 off = blockSums[b] + (t>0 ? lds[t-1] : 0u);
  u32 base = (u32)(b*1024 + t*4);
  offsets[base+0]=off; cursor[base+0]=off; off += c4.x;
  offsets[base+1]=off; cursor[base+1]=off; off += c4.y;
  offsets[base+2]=off; cursor[base+2]=off; off += c4.z;
  offsets[base+3]=off; cursor[base+3]=off; off += c4.w;
  if(base+4 == SS) offsets[SS] = off;
}

__global__ __launch_bounds__(256) void k_scatter(const u32* __restrict__ lin,
                                                 u32* __restrict__ cursor,
                                                 u32* __restrict__ order){
  int p = blockIdx.x*256 + threadIdx.x;
  u32 v = lin[p];
  u32 pos = atomicAdd(&cursor[v], 1u);
  order[pos] = p;
}

// ---------------- weight prep: bf16 transposed ----------------
__global__ __launch_bounds__(256) void k_prep(const float* __restrict__ W2,
    const float* __restrict__ W3, const float* __restrict__ W4,
    const float* __restrict__ Wc,
    u16* __restrict__ W2t, u16* __restrict__ W3t, u16* __restrict__ W4t,
    u16* __restrict__ Wct){
  int i = blockIdx.x*256 + threadIdx.x;
  if(i < 8192){
    int k = i >> 7, n = i & 127;
    W2t[n*64 + k] = f2bf(W2[i]);
  } else if(i < 8192+32768){
    int j = i - 8192;
    int k = j >> 8, n = j & 255;
    W3t[n*128 + k] = f2bf(W3[j]);
  } else if(i < 8192+32768+65536){
    int j = i - (8192+32768);
    int k = j >> 8, n = j & 255;
    W4t[n*256 + k] = f2bf(W4[j]);
  } else if(i < 8192+32768+65536+16384){
    int j = i - (8192+32768+65536);
    int k = j >> 6, n = j & 63;
    Wct[n*256 + k] = f2bf(Wc[j]);
  }
}

// ---------------- stats0: feats stats + feats dump ----------------
__global__ __launch_bounds__(256) void k_stats0(const float* __restrict__ pts,
    const u32* __restrict__ lin, const u32* __restrict__ counts,
    const float* __restrict__ vsum, float* __restrict__ feats,
    float* __restrict__ sum0, float* __restrict__ sq0){
  int p = blockIdx.x*256 + threadIdx.x;
  float f[8]; u32 v;
  point_feats(p, pts, lin, counts, vsum, f, &v);
  float4* fo = (float4*)&feats[(size_t)p*8];
  fo[0] = make_float4(f[0],f[1],f[2],f[3]);
  fo[1] = make_float4(f[4],f[5],f[6],f[7]);
  __shared__ float lsum[4][8], lsq[4][8];
  int lane = threadIdx.x & 63, wv = threadIdx.x >> 6;
  #pragma unroll
  for(int c=0;c<8;c++){
    float s = f[c], q = f[c]*f[c];
    #pragma unroll
    for(int d=32; d; d>>=1){ s += __shfl_xor(s,d); q += __shfl_xor(q,d); }
    if(lane==0){ lsum[wv][c]=s; lsq[wv][c]=q; }
  }
  __syncthreads();
  if(threadIdx.x<8){
    float s=0.f,q=0.f;
    for(int g=0;g<4;g++){ s+=lsum[g][threadIdx.x]; q+=lsq[g][threadIdx.x]; }
    atomicAdd(&sum0[threadIdx.x], s);
    atomicAdd(&sq0[threadIdx.x], q);
  }
}

// ---------------- fold BN stats -> (a,c) (proven) ----------------
__global__ void k_fold(const float* __restrict__ sum, const float* __restrict__ sq,
                       const float* __restrict__ g, const float* __restrict__ b,
                       float* __restrict__ a, float* __restrict__ c, int C){
  int i = blockIdx.x*64 + threadIdx.x;
  if(i < C){
    float m = sum[i]*(1.0f/NPTS);
    float v = sq[i]*(1.0f/NPTS) - m*m;
    v = fmaxf(v, 0.0f);
    float ai = g[i] / sqrtf(v + EPSV);
    a[i] = ai;
    c[i] = b[i] - m*ai;
  }
}

// ---------------- stats1b: channel-streaming z1 stats ----------------
// thread = channel (lane), wave streams its point range; no shuffle butterflies.
__global__ __launch_bounds__(256) void k_stats1b(const float* __restrict__ feats,
    const float* __restrict__ a0, const float* __restrict__ c0,
    const float* __restrict__ W1,
    float* __restrict__ sum1, float* __restrict__ sq1){
  __shared__ float ls[4][64], lq[4][64];
  int tid = threadIdx.x, lane = tid & 63, wv = tid >> 6;
  float w1c[8], a0r[8], c0r[8];
  #pragma unroll
  for(int k=0;k<8;k++){ w1c[k]=W1[k*64+lane]; a0r[k]=a0[k]; c0r[k]=c0[k]; }
  float s = 0.f, q = 0.f;
  size_t p0 = (size_t)blockIdx.x*1024 + (size_t)wv*256;
  for(int pp=0; pp<256; pp++){
    const float* fr = &feats[(p0+pp)*8];
    float z = 0.f;
    #pragma unroll
    for(int k=0;k<8;k++) z += (a0r[k]*fr[k] + c0r[k]) * w1c[k];
    s += z; q += z*z;
  }
  ls[wv][lane]=s; lq[wv][lane]=q;
  __syncthreads();
  if(tid < 64){
    float S = ls[0][tid]+ls[1][tid]+ls[2][tid]+ls[3][tid];
    float Q = lq[0][tid]+lq[1][tid]+lq[2][tid]+lq[3][tid];
    atomicAdd(&sum1[tid], S);
    atomicAdd(&sq1[tid], Q);
  }
}

// ---------------- mstats2: z2 stats via MFMA (feats-fed) ----------
__global__ __launch_bounds__(256,2) void k_mstats2(
    const float* __restrict__ feats,
    const float* __restrict__ a0, const float* __restrict__ c0,
    const float* __restrict__ a1, const float* __restrict__ c1,
    const float* __restrict__ W1, const u16* __restrict__ W2t,
    float* __restrict__ sum2, float* __restrict__ sq2){
  __shared__ u16 T1[256*72];
  int tid = threadIdx.x, lane = tid&63, wid = tid>>6, l15 = lane&15, lg = lane>>4;
  float s2[2] = {0.f,0.f}, q2[2] = {0.f,0.f};

  for(int cch=0; cch<4; cch++){
    int p = blockIdx.x*1024 + cch*256 + tid;
    const float4* fr = (const float4*)&feats[(size_t)p*8];
    float4 fa = fr[0], fb = fr[1];
    float f[8] = {fa.x,fa.y,fa.z,fa.w,fb.x,fb.y,fb.z,fb.w};
    float y0[8];
    #pragma unroll
    for(int k=0;k<8;k++) y0[k] = a0[k]*f[k] + c0[k];
    u32 pk[32];
    #pragma unroll
    for(int jj=0;jj<32;jj++){
      float s0=0.f, s1=0.f;
      #pragma unroll
      for(int k=0;k<8;k++){ s0 += y0[k]*W1[k*64+2*jj]; s1 += y0[k]*W1[k*64+2*jj+1]; }
      float v0f = fmaxf(a1[2*jj]*s0   + c1[2*jj],   0.f);
      float v1f = fmaxf(a1[2*jj+1]*s1 + c1[2*jj+1], 0.f);
      pk[jj] = (u32)f2bf(v0f) | ((u32)f2bf(v1f)<<16);
    }
    __syncthreads();
    {
      uint4* dst = (uint4*)&T1[tid*72];
      #pragma unroll
      for(int q=0;q<8;q++) dst[q] = make_uint4(pk[4*q],pk[4*q+1],pk[4*q+2],pk[4*q+3]);
    }
    __syncthreads();
    #pragma unroll
    for(int ci=0; ci<2; ci++){
      int ch = (wid + 4*ci)*16 + l15;
      const u16* wb = W2t + (size_t)ch*64 + lg*8;
      bf16x8 b0 = *(const bf16x8*)(wb);
      bf16x8 b1 = *(const bf16x8*)(wb + 32);
      for(int rt=0; rt<16; rt++){
        const u16* ap = T1 + (rt*16 + l15)*72 + lg*8;
        bf16x8 af0 = *(const bf16x8*)(ap);
        bf16x8 af1 = *(const bf16x8*)(ap + 32);
        f32x4 acc = {0.f,0.f,0.f,0.f};
        acc = __builtin_amdgcn_mfma_f32_16x16x32_bf16(af0, b0, acc, 0,0,0);
        acc = __builtin_amdgcn_mfma_f32_16x16x32_bf16(af1, b1, acc, 0,0,0);
        #pragma unroll
        for(int i=0;i<4;i++){ s2[ci] += acc[i]; q2[ci] += acc[i]*acc[i]; }
      }
    }
  }
  #pragma unroll
  for(int ci=0; ci<2; ci++){
    float s = s2[ci], q = q2[ci];
    s += __shfl_xor(s,16); s += __shfl_xor(s,32);
    q += __shfl_xor(q,16); q += __shfl_xor(q,32);
    if(lg == 0){
      int ch = (wid + 4*ci)*16 + l15;
      atomicAdd(&sum2[ch], s);
      atomicAdd(&sq2[ch], q);
    }
  }
}

// ---------------- chain2: 512-thread version (8 waves/CU), feats-fed ------------
__global__ __launch_bounds__(512,1) void k_chain2(
    const float* __restrict__ feats, const u32* __restrict__ order,
    const float* __restrict__ a0, const float* __restrict__ c0,
    const float* __restrict__ a1, const float* __restrict__ c1,
    const float* __restrict__ a2, const float* __restrict__ c2,
    const float* __restrict__ W1, const u16* __restrict__ W2t,
    const u16* __restrict__ W3t,
    u32* __restrict__ y2s,
    float* __restrict__ sum3, float* __restrict__ sq3){
  __shared__ u16 T1[256*72];
  __shared__ u16 T2[256*136];
  int tid = threadIdx.x, lane = tid&63, wid = tid>>6, l15 = lane&15, lg = lane>>4;
  float s3[2] = {0.f,0.f}, q3[2] = {0.f,0.f};

  for(int cch=0; cch<4; cch++){
    u32 pk[32];
    if(tid < 256){
      int rr = blockIdx.x*1024 + cch*256 + tid;
      int p = (int)order[rr];
      const float4* fr = (const float4*)&feats[(size_t)p*8];
      float4 fa = fr[0], fb = fr[1];
      float f[8] = {fa.x,fa.y,fa.z,fa.w,fb.x,fb.y,fb.z,fb.w};
      float y0[8];
      #pragma unroll
      for(int k=0;k<8;k++) y0[k] = a0[k]*f[k] + c0[k];
      #pragma unroll
      for(int jj=0;jj<32;jj++){
        float s0=0.f, s1=0.f;
        #pragma unroll
        for(int k=0;k<8;k++){ s0 += y0[k]*W1[k*64+2*jj]; s1 += y0[k]*W1[k*64+2*jj+1]; }
        float v0f = fmaxf(a1[2*jj]*s0   + c1[2*jj],   0.f);
        float v1f = fmaxf(a1[2*jj+1]*s1 + c1[2*jj+1], 0.f);
        pk[jj] = (u32)f2bf(v0f) | ((u32)f2bf(v1f)<<16);
      }
    }
    __syncthreads();
    if(tid < 256){
      uint4* dst = (uint4*)&T1[tid*72];
      #pragma unroll
      for(int q=0;q<8;q++) dst[q] = make_uint4(pk[4*q],pk[4*q+1],pk[4*q+2],pk[4*q+3]);
    }
    __syncthreads();
    // L2: T1(256x64) @ W2t -> bn2relu -> T2(256x128); 1 ch-tile per wave
    {
      int ch = wid*16 + l15;
      const u16* wb = W2t + (size_t)ch*64 + lg*8;
      bf16x8 b0 = *(const bf16x8*)(wb);
      bf16x8 b1 = *(const bf16x8*)(wb + 32);
      float a2v = a2[ch], c2v = c2[ch];
      for(int rt=0; rt<16; rt++){
        const u16* ap = T1 + (rt*16 + l15)*72 + lg*8;
        bf16x8 af0 = *(const bf16x8*)(ap);
        bf16x8 af1 = *(const bf16x8*)(ap + 32);
        f32x4 acc = {0.f,0.f,0.f,0.f};
        acc = __builtin_amdgcn_mfma_f32_16x16x32_bf16(af0, b0, acc, 0,0,0);
        acc = __builtin_amdgcn_mfma_f32_16x16x32_bf16(af1, b1, acc, 0,0,0);
        int rbase = rt*16 + lg*4;
        #pragma unroll
        for(int i=0;i<4;i++)
          T2[(rbase+i)*136 + ch] = f2bf(fmaxf(a2v*acc[i] + c2v, 0.f));
      }
    }
    __syncthreads();
    {
      const u32* T2w = (const u32*)T2;
      u32 base = (u32)blockIdx.x*1024u + (u32)cch*256u;
      for(int i=tid; i<256*64; i+=512){
        int row = i>>6, w = i&63;
        y2s[(size_t)(base+row)*64 + w] = T2w[row*68 + w];
      }
    }
    // L3: z3 = T2(256x128) @ W3t; 2 ch-tiles per wave; stats only
    #pragma unroll
    for(int ci=0; ci<2; ci++){
      int ch = (wid + 8*ci)*16 + l15;
      const u16* wb = W3t + (size_t)ch*128 + lg*8;
      bf16x8 b[4];
      #pragma unroll
      for(int ks=0; ks<4; ks++) b[ks] = *(const bf16x8*)(wb + ks*32);
      for(int rt=0; rt<16; rt++){
        const u16* ap = T2 + (rt*16 + l15)*136 + lg*8;
        f32x4 acc = {0.f,0.f,0.f,0.f};
        #pragma unroll
        for(int ks=0; ks<4; ks++){
          bf16x8 af = *(const bf16x8*)(ap + ks*32);
          acc = __builtin_amdgcn_mfma_f32_16x16x32_bf16(af, b[ks], acc, 0,0,0);
        }
        #pragma unroll
        for(int i=0;i<4;i++){ s3[ci] += acc[i]; q3[ci] += acc[i]*acc[i]; }
      }
    }
  }
  #pragma unroll
  for(int ci=0; ci<2; ci++){
    float s = s3[ci], q = q3[ci];
    s += __shfl_xor(s,16); s += __shfl_xor(s,32);
    q += __shfl_xor(q,16); q += __shfl_xor(q,32);
    if(lg == 0){
      int ch = (wid + 8*ci)*16 + l15;
      atomicAdd(&sum3[ch], s);
      atomicAdd(&sq3[ch], q);
    }
  }
}

// ---------------- mega6 (proven r12) ----------------
__global__ __launch_bounds__(512,4) void k_mega6(
    const u32* __restrict__ offsets, const u32* __restrict__ y2s,
    const float* __restrict__ a3, const float* __restrict__ c3,
    const u16* __restrict__ W3t, const u16* __restrict__ W4t,
    const u16* __restrict__ Wct,
    const float* __restrict__ b4, const float* __restrict__ bc,
    u16* __restrict__ comp){
  __shared__ __align__(16) char SM[78208];
  u16* T3  = (u16*)(SM);            // [80][264] 42240
  u16* T2s = (u16*)(SM + 42240);    // [80][136] 21760 (staging; dead after L3)
  u16* Tz0 = (u16*)(SM + 42240);    // [80][72] 11520
  u16* Tz1 = (u16*)(SM + 53760);    // [80][72] 11520
  u16* TA  = (u16*)(SM + 65280);    // [80][72] 11520
  u32* vst = (u32*)(SM + 76800);    // [VCAP+1]
  float* bb = (float*)(SM + 77152); // [256] b4 preload
  u32* hdr = (u32*)(SM + 78176);    // [4]

  int tid = threadIdx.x, lane = tid & 63, wid = tid >> 6;
  int l15 = lane & 15, lg = lane >> 4;
  int cg = wid & 3, rh = wid >> 2;
  int nvt = rh ? 2 : 3, vt0 = rh ? 3 : 0;

  if(tid == 0){
    u32 t0 = (u32)blockIdx.x * 64u;
    u32 lo=0, hi=SS;
    while(lo<hi){ u32 mid=(lo+hi)>>1; if(offsets[mid] < t0) lo=mid+1; else hi=mid; }
    u32 vlo = lo, vhi;
    if(blockIdx.x == NB-1) vhi = SS;
    else {
      u32 t1 = t0 + 64u;
      lo = vlo; hi = SS;
      while(lo<hi){ u32 mid=(lo+hi)>>1; if(offsets[mid] < t1) lo=mid+1; else hi=mid; }
      vhi = lo;
    }
    hdr[0]=vlo; hdr[1]=vhi; hdr[2]=offsets[vlo]; hdr[3]=offsets[vhi];
  }
  if(tid < 256) bb[tid] = b4[tid];
  __syncthreads();
  u32 vlo=hdr[0], vhi=hdr[1], start=hdr[2], end=hdr[3];
  int R = (int)(end - start); if(R > RCAP) R = RCAP;
  int V = (int)(vhi - vlo);   if(V > VCAP) V = VCAP;

  if(tid <= VCAP){
    u32 o = (tid <= V) ? offsets[vlo + tid] : end;
    int s = (int)(o - start); if(s > RCAP) s = RCAP;
    vst[tid] = (u32)s;
  }

  {
    u32* T2w = (u32*)T2s;
    for(int i=tid; i<RCAP*64; i+=512){
      int row = i>>6, w = i&63;
      u32 val = (row < R) ? y2s[(size_t)(start+row)*64 + w] : 0u;
      T2w[row*68 + w] = val;
    }
  }
  __syncthreads();

  for(int ci=0; ci<2; ci++){
    int ch = (wid + 8*ci)*16 + l15;
    const u16* wb = W3t + (size_t)ch*128 + lg*8;
    bf16x8 b[4];
    #pragma unroll
    for(int ks=0; ks<4; ks++) b[ks] = *(const bf16x8*)(wb + ks*32);
    float a3v = a3[ch], c3v = c3[ch];
    for(int rt=0; rt<5; rt++){
      const u16* ap = T2s + (rt*16 + l15)*136 + lg*8;
      f32x4 acc = {0.f,0.f,0.f,0.f};
      #pragma unroll
      for(int ks=0; ks<4; ks++){
        bf16x8 af = *(const bf16x8*)(ap + ks*32);
        acc = __builtin_amdgcn_mfma_f32_16x16x32_bf16(af, b[ks], acc, 0,0,0);
      }
      int rbase = rt*16 + lg*4;
      #pragma unroll
      for(int i=0;i<4;i++)
        T3[(rbase+i)*264 + ch] = f2bf(fmaxf(a3v*acc[i] + c3v, 0.f));
    }
  }
  __syncthreads();

  f32x4 acc3[3];
  #pragma unroll
  for(int i=0;i<3;i++) acc3[i] = (f32x4){0.f,0.f,0.f,0.f};
  int ch4 = cg*16 + l15;

  for(int pr=0; pr<2; pr++){
    int oc0 = 2*pr, oc1 = 2*pr + 1;
    {
      const u16* wb0 = W4t + (size_t)(oc0*64 + ch4)*256 + lg*8;
      const u16* wb1 = W4t + (size_t)(oc1*64 + ch4)*256 + lg*8;
      bf16x8 b0[8], b1[8];
      #pragma unroll
      for(int ks=0; ks<8; ks++){
        b0[ks] = *(const bf16x8*)(wb0 + ks*32);
        b1[ks] = *(const bf16x8*)(wb1 + ks*32);
      }
      int rtB = rh ? 3 : 0, rtE = rh ? 5 : 3;
      for(int rt=rtB; rt<rtE; rt++){
        const u16* ap = T3 + (rt*16 + l15)*264 + lg*8;
        f32x4 aA = {0.f,0.f,0.f,0.f}, aB = {0.f,0.f,0.f,0.f};
        #pragma unroll
        for(int ks=0; ks<8; ks++){
          bf16x8 af = *(const bf16x8*)(ap + ks*32);
          aA = __builtin_amdgcn_mfma_f32_16x16x32_bf16(af, b0[ks], aA, 0,0,0);
          aB = __builtin_amdgcn_mfma_f32_16x16x32_bf16(af, b1[ks], aB, 0,0,0);
        }
        int rbase = rt*16 + lg*4;
        #pragma unroll
        for(int i=0;i<4;i++){
          Tz0[(rbase+i)*72 + ch4] = f2bf(aA[i]);
          Tz1[(rbase+i)*72 + ch4] = f2bf(aB[i]);
        }
      }
    }
    __syncthreads();
    for(int i=tid; i<VCAP*64; i+=512){
      int v = i>>6, k = i&63;
      u32 r0 = vst[v], r1 = vst[v+1];
      u16 outv = 0;
      if(r1 > r0){
        float m = -3.0e38f;
        for(u32 r=r0; r<r1; r++) m = fmaxf(m, bf2f(Tz0[r*72+k]));
        outv = f2bf(m + bb[oc0*64+k]);
      }
      TA[v*72+k] = outv;
    }
    __syncthreads();
    {
      const u16* wb = Wct + (size_t)ch4*256 + oc0*64 + lg*8;
      bf16x8 c0f = *(const bf16x8*)(wb);
      bf16x8 c1f = *(const bf16x8*)(wb + 32);
      #pragma unroll
      for(int s=0; s<3; s++){
        if(s < nvt){
          int vt = vt0 + s;
          const u16* ap = TA + (vt*16 + l15)*72 + lg*8;
          bf16x8 af0 = *(const bf16x8*)(ap);
          bf16x8 af1 = *(const bf16x8*)(ap + 32);
          acc3[s] = __builtin_amdgcn_mfma_f32_16x16x32_bf16(af0, c0f, acc3[s], 0,0,0);
          acc3[s] = __builtin_amdgcn_mfma_f32_16x16x32_bf16(af1, c1f, acc3[s], 0,0,0);
        }
      }
    }
    __syncthreads();
    for(int i=tid; i<VCAP*64; i+=512){
      int v = i>>6, k = i&63;
      u32 r0 = vst[v], r1 = vst[v+1];
      u16 outv = 0;
      if(r1 > r0){
        float m = -3.0e38f;
        for(u32 r=r0; r<r1; r++) m = fmaxf(m, bf2f(Tz1[r*72+k]));
        outv = f2bf(m + bb[oc1*64+k]);
      }
      TA[v*72+k] = outv;
    }
    __syncthreads();
    {
      const u16* wb = Wct + (size_t)ch4*256 + oc1*64 + lg*8;
      bf16x8 c0f = *(const bf16x8*)(wb);
      bf16x8 c1f = *(const bf16x8*)(wb + 32);
      #pragma unroll
      for(int s=0; s<3; s++){
        if(s < nvt){
          int vt = vt0 + s;
          const u16* ap = TA + (vt*16 + l15)*72 + lg*8;
          bf16x8 af0 = *(const bf16x8*)(ap);
          bf16x8 af1 = *(const bf16x8*)(ap + 32);
          acc3[s] = __builtin_amdgcn_mfma_f32_16x16x32_bf16(af0, c0f, acc3[s], 0,0,0);
          acc3[s] = __builtin_amdgcn_mfma_f32_16x16x32_bf16(af1, c1f, acc3[s], 0,0,0);
        }
      }
    }
    __syncthreads();
  }

  {
    float bcv = bc[ch4];
    #pragma unroll
    for(int s=0; s<3; s++){
      if(s < nvt){
        int vt = vt0 + s;
        int vbase = vt*16 + lg*4;
        #pragma unroll
        for(int i=0;i<4;i++){
          int vox = vbase + i;
          if(vox < V){
            bool nz = vst[vox+1] > vst[vox];
            float val = nz ? fmaxf(acc3[s][i] + bcv, 0.f) : 0.f;
            comp[(size_t)(vlo+vox)*64 + ch4] = f2bf(val);
          }
        }
      }
    }
  }
}

// ---------------- residual image from comp (proven) ----------------
__global__ __launch_bounds__(256) void k_resid(const u16* __restrict__ comp,
                                               float* __restrict__ out){
  __shared__ u32 cl[4*128*32];
  int t = threadIdx.x;
  int blk = blockIdx.x;
  int wq = blk & 3, h = (blk>>2) & 63, b = blk>>8;
  int w0 = wq*128;
  for(int fr=0; fr<4; fr++){
    const u32* src = (const u32*)comp + ((size_t)(((b*4+fr)*64 + h)*512 + w0))*32;
    for(int i=t; i<4096; i+=256){
      int vox = i>>5, wd = i&31;
      cl[fr*4096 + vox*32 + (wd ^ (vox&31))] = src[i];
    }
  }
  __syncthreads();
  int wl = t & 127, half = t >> 7;
  int mv = wl & 31;
  for(int ch = half; ch < 64; ch += 2){
    u32 wr3 = cl[3*4096 + wl*32 + ((ch>>1) ^ mv)];
    float r3 = bf2f((ch&1) ? (u16)(wr3>>16) : (u16)(wr3&0xFFFFu));
    #pragma unroll
    for(int fr=0; fr<3; fr++){
      u32 wrf = cl[fr*4096 + wl*32 + ((ch>>1) ^ mv)];
      float vf = bf2f((ch&1) ? (u16)(wrf>>16) : (u16)(wrf&0xFFFFu));
      out[(((size_t)(b*192 + fr*64 + ch))*64 + h)*512 + w0 + wl] = r3 - vf;
    }
  }
}

// ------------------------------- launcher -------------------------------------
extern "C" void kernel_launch(void* const* d_in, const int* in_sizes, int n_in,
                              void* d_out, int out_size, void* d_ws, size_t ws_size,
                              hipStream_t stream){
  const float* pts  = (const float*)d_in[0];
  const int*  coors = (const int*)d_in[1];
  const float* g0 = (const float*)d_in[2];
  const float* b0 = (const float*)d_in[3];
  const float* W1 = (const float*)d_in[4];
  const float* g1 = (const float*)d_in[5];
  const float* b1 = (const float*)d_in[6];
  const float* W2 = (const float*)d_in[7];
  const float* g2 = (const float*)d_in[8];
  const float* b2 = (const float*)d_in[9];
  const float* W3 = (const float*)d_in[10];
  const float* g3 = (const float*)d_in[11];
  const float* b3 = (const float*)d_in[12];
  const float* W4 = (const float*)d_in[13];
  const float* b4 = (const float*)d_in[14];
  const float* Wc = (const float*)d_in[15];
  const float* bc = (const float*)d_in[16];
  float* out = (float*)d_out;
  (void)in_sizes; (void)n_in; (void)out_size; (void)ws_size;

  char* ws = (char*)d_ws;
  size_t off = 0;
  auto alloc = [&](size_t bytes)->void*{
    void* p = ws + off;
    off += (bytes + 255) & ~(size_t)255;
    return p;
  };
  u32*  counts  = (u32*)alloc((size_t)SS*4);
  float* vsum   = (float*)alloc((size_t)SS*3*4);
  float* stats  = (float*)alloc(8192);
  size_t zero_bytes = off;
  u32*  lin     = (u32*)alloc((size_t)NPTS*4);
  u32*  offsets = (u32*)alloc((size_t)(SS+1)*4);
  u32*  cursor  = (u32*)alloc((size_t)SS*4);
  u32*  order   = (u32*)alloc((size_t)NPTS*4);
  u32*  blockSums = (u32*)alloc(1024);
  u16*  comp    = (u16*)alloc((size_t)SS*64*2);
  u16*  W2t = (u16*)alloc(8192*2);
  u16*  W3t = (u16*)alloc(32768*2);
  u16*  W4t = (u16*)alloc(65536*2);
  u16*  Wct = (u16*)alloc(16384*2);
  float* feats = (float*)alloc((size_t)NPTS*8*4);   // 16 MB
  u32*  y2s = (u32*)alloc((size_t)NPTS*64*4);       // 134 MB (total ~200 MB <= 216 proven)

  float* sum0=stats+0,   *sq0=stats+8,    *a0=stats+16,   *c0=stats+24;
  float* sum1=stats+32,  *sq1=stats+96,   *a1=stats+160,  *c1=stats+224;
  float* sum2=stats+288, *sq2=stats+416,  *a2=stats+544,  *c2=stats+672;
  float* sum3=stats+800, *sq3=stats+1056, *a3=stats+1312, *c3=stats+1568;

  hipMemsetAsync(d_ws, 0, zero_bytes, stream);

  k_prep   <<<480, 256,0,stream>>>(W2, W3, W4, Wc, W2t, W3t, W4t, Wct);
  k_lin    <<<2048,256,0,stream>>>(pts, coors, lin, counts, vsum);
  k_scan_a <<<256, 256,0,stream>>>(counts, blockSums);
  k_scan_b <<<1,   64, 0,stream>>>(blockSums);
  k_scan_c <<<256, 256,0,stream>>>(counts, blockSums, offsets, cursor);
  k_scatter<<<2048,256,0,stream>>>(lin, cursor, order);

  k_stats0 <<<2048,256,0,stream>>>(pts, lin, counts, vsum, feats, sum0, sq0);
  k_fold   <<<1,   64, 0,stream>>>(sum0, sq0, g0, b0, a0, c0, 8);
  k_stats1b<<<512, 256,0,stream>>>(feats, a0, c0, W1, sum1, sq1);
  k_fold   <<<1,   64, 0,stream>>>(sum1, sq1, g1, b1, a1, c1, 64);
  k_mstats2<<<512, 256,0,stream>>>(feats, a0,c0,a1,c1, W1, W2t, sum2, sq2);
  k_fold   <<<2,   64, 0,stream>>>(sum2, sq2, g2, b2, a2, c2, 128);
  k_chain2 <<<512, 512,0,stream>>>(feats, order, a0,c0,a1,c1,a2,c2, W1, W2t, W3t,
                                   y2s, sum3, sq3);
  k_fold   <<<4,   64, 0,stream>>>(sum3, sq3, g3, b3, a3, c3, 256);

  k_mega6  <<<NB,  512,0,stream>>>(offsets, y2s, a3,c3, W3t, W4t, Wct, b4, bc, comp);
  k_resid  <<<512, 256,0,stream>>>(comp, out);
}

// Round 14
// 967.329 us; speedup vs baseline: 1.9589x; 1.1016x over previous
//
#include <hip/hip_runtime.h>
#include <hip/hip_bf16.h>
#include <stdint.h>

typedef unsigned int u32;
typedef unsigned short u16;
typedef __attribute__((ext_vector_type(8))) short bf16x8;
typedef __attribute__((ext_vector_type(4))) float f32x4;

#define NPTS 524288
#define FF 4
#define HH 64
#define WW 512
#define SS 262144
#define EPSV 1e-5f
#define NB 8192
#define RCAP 80
#define VCAP 80

__device__ __forceinline__ float bf2f(u16 h){ return __uint_as_float(((u32)h)<<16); }
__device__ __forceinline__ u16 f2bf(float f){
  u32 u = __float_as_uint(f);
  return (u16)((u + 0x7FFFu + ((u>>16)&1u)) >> 16);   // RNE (monotone)
}
// compiler-lowered float->bf16 (HIP API; monotone rounding)
__device__ __forceinline__ u16 f2bfh(float f){
  __hip_bfloat16 h = __float2bfloat16(f);
  u16 r; __builtin_memcpy(&r, &h, 2); return r;
}

__device__ __forceinline__ void point_feats(int p, const float* __restrict__ pts,
    const u32* __restrict__ lin, const u32* __restrict__ counts,
    const float* __restrict__ vsum, float f[8], u32* vout){
  float4 pt = ((const float4*)pts)[p];
  u32 v = lin[p];
  float cnt = fmaxf((float)counts[v], 1.0f);
  float inv = 1.0f/cnt;
  float mx = vsum[v*3+0]*inv, my = vsum[v*3+1]*inv, mz = vsum[v*3+2]*inv;
  float dist = sqrtf(pt.x*pt.x + pt.y*pt.y + pt.z*pt.z);
  f[0]=pt.x; f[1]=pt.y; f[2]=pt.z; f[3]=pt.w; f[4]=dist;
  f[5]=pt.x-mx; f[6]=pt.y-my; f[7]=pt.z-mz;
  *vout = v;
}

// ---------------- pass 1: linear voxel id + counts + coord sums ----------------
__global__ __launch_bounds__(256) void k_lin(const float* __restrict__ pts,
                                             const int* __restrict__ coors,
                                             u32* __restrict__ lin,
                                             u32* __restrict__ counts,
                                             float* __restrict__ vsum){
  int p = blockIdx.x*256 + threadIdx.x;
  int4 c = ((const int4*)coors)[p];
  u32 v = ((u32)((c.x*FF + c.y)*HH + c.z))*WW + (u32)c.w;
  lin[p] = v;
  atomicAdd(&counts[v], 1u);
  float4 pt = ((const float4*)pts)[p];
  atomicAdd(&vsum[v*3+0], pt.x);
  atomicAdd(&vsum[v*3+1], pt.y);
  atomicAdd(&vsum[v*3+2], pt.z);
}

// ---------------- counting-sort scan ----------------
__global__ __launch_bounds__(256) void k_scan_a(const u32* __restrict__ counts,
                                                u32* __restrict__ blockSums){
  __shared__ u32 lds[256];
  int b = blockIdx.x, t = threadIdx.x;
  uint4 c4 = ((const uint4*)counts)[b*256 + t];
  lds[t] = c4.x + c4.y + c4.z + c4.w;
  __syncthreads();
  for(int s=128; s>0; s>>=1){ if(t<s) lds[t] += lds[t+s]; __syncthreads(); }
  if(t==0) blockSums[b] = lds[0];
}

__global__ void k_scan_b(u32* blockSums){
  if(threadIdx.x==0){
    u32 run = 0;
    for(int i=0;i<256;i++){ u32 v = blockSums[i]; blockSums[i] = run; run += v; }
  }
}

__global__ __launch_bounds__(256) void k_scan_c(const u32* __restrict__ counts,
                                                const u32* __restrict__ blockSums,
                                                u32* __restrict__ offsets,
                                                u32* __restrict__ cursor){
  __shared__ u32 lds[256];
  int b = blockIdx.x, t = threadIdx.x;
  uint4 c4 = ((const uint4*)counts)[b*256 + t];
  u32 mysum = c4.x + c4.y + c4.z + c4.w;
  lds[t] = mysum;
  __syncthreads();
  for(int d=1; d<256; d<<=1){
    u32 v = (t>=d) ? lds[t-d] : 0u;
    __syncthreads();
    lds[t] += v;
    __syncthreads();
  }
  u32 off = blockSums[b] + (t>0 ? lds[t-1] : 0u);
  u32 base = (u32)(b*1024 + t*4);
  offsets[base+0]=off; cursor[base+0]=off; off += c4.x;
  offsets[base+1]=off; cursor[base+1]=off; off += c4.y;
  offsets[base+2]=off; cursor[base+2]=off; off += c4.z;
  offsets[base+3]=off; cursor[base+3]=off; off += c4.w;
  if(base+4 == SS) offsets[SS] = off;
}

__global__ __launch_bounds__(256) void k_scatter(const u32* __restrict__ lin,
                                                 u32* __restrict__ cursor,
                                                 u32* __restrict__ order){
  int p = blockIdx.x*256 + threadIdx.x;
  u32 v = lin[p];
  u32 pos = atomicAdd(&cursor[v], 1u);
  order[pos] = p;
}

// ---------------- weight prep: bf16 transposed ----------------
__global__ __launch_bounds__(256) void k_prep(const float* __restrict__ W2,
    const float* __restrict__ W3, const float* __restrict__ W4,
    const float* __restrict__ Wc,
    u16* __restrict__ W2t, u16* __restrict__ W3t, u16* __restrict__ W4t,
    u16* __restrict__ Wct){
  int i = blockIdx.x*256 + threadIdx.x;
  if(i < 8192){
    int k = i >> 7, n = i & 127;
    W2t[n*64 + k] = f2bf(W2[i]);
  } else if(i < 8192+32768){
    int j = i - 8192;
    int k = j >> 8, n = j & 255;
    W3t[n*128 + k] = f2bf(W3[j]);
  } else if(i < 8192+32768+65536){
    int j = i - (8192+32768);
    int k = j >> 8, n = j & 255;
    W4t[n*256 + k] = f2bf(W4[j]);
  } else if(i < 8192+32768+65536+16384){
    int j = i - (8192+32768+65536);
    int k = j >> 6, n = j & 63;
    Wct[n*256 + k] = f2bf(Wc[j]);
  }
}

// ---------------- stats0: feats stats + feats dump ----------------
__global__ __launch_bounds__(256) void k_stats0(const float* __restrict__ pts,
    const u32* __restrict__ lin, const u32* __restrict__ counts,
    const float* __restrict__ vsum, float* __restrict__ feats,
    float* __restrict__ sum0, float* __restrict__ sq0){
  int p = blockIdx.x*256 + threadIdx.x;
  float f[8]; u32 v;
  point_feats(p, pts, lin, counts, vsum, f, &v);
  float4* fo = (float4*)&feats[(size_t)p*8];
  fo[0] = make_float4(f[0],f[1],f[2],f[3]);
  fo[1] = make_float4(f[4],f[5],f[6],f[7]);
  __shared__ float lsum[4][8], lsq[4][8];
  int lane = threadIdx.x & 63, wv = threadIdx.x >> 6;
  #pragma unroll
  for(int c=0;c<8;c++){
    float s = f[c], q = f[c]*f[c];
    #pragma unroll
    for(int d=32; d; d>>=1){ s += __shfl_xor(s,d); q += __shfl_xor(q,d); }
    if(lane==0){ lsum[wv][c]=s; lsq[wv][c]=q; }
  }
  __syncthreads();
  if(threadIdx.x<8){
    float s=0.f,q=0.f;
    for(int g=0;g<4;g++){ s+=lsum[g][threadIdx.x]; q+=lsq[g][threadIdx.x]; }
    atomicAdd(&sum0[threadIdx.x], s);
    atomicAdd(&sq0[threadIdx.x], q);
  }
}

// ---------------- fold BN stats -> (a,c) (proven) ----------------
__global__ void k_fold(const float* __restrict__ sum, const float* __restrict__ sq,
                       const float* __restrict__ g, const float* __restrict__ b,
                       float* __restrict__ a, float* __restrict__ c, int C){
  int i = blockIdx.x*64 + threadIdx.x;
  if(i < C){
    float m = sum[i]*(1.0f/NPTS);
    float v = sq[i]*(1.0f/NPTS) - m*m;
    v = fmaxf(v, 0.0f);
    float ai = g[i] / sqrtf(v + EPSV);
    a[i] = ai;
    c[i] = b[i] - m*ai;
  }
}

// ---------------- stats1b: channel-streaming z1 stats (proven r13) --------------
__global__ __launch_bounds__(256) void k_stats1b(const float* __restrict__ feats,
    const float* __restrict__ a0, const float* __restrict__ c0,
    const float* __restrict__ W1,
    float* __restrict__ sum1, float* __restrict__ sq1){
  __shared__ float ls[4][64], lq[4][64];
  int tid = threadIdx.x, lane = tid & 63, wv = tid >> 6;
  float w1c[8], a0r[8], c0r[8];
  #pragma unroll
  for(int k=0;k<8;k++){ w1c[k]=W1[k*64+lane]; a0r[k]=a0[k]; c0r[k]=c0[k]; }
  float s = 0.f, q = 0.f;
  size_t p0 = (size_t)blockIdx.x*1024 + (size_t)wv*256;
  for(int pp=0; pp<256; pp++){
    const float* fr = &feats[(p0+pp)*8];
    float z = 0.f;
    #pragma unroll
    for(int k=0;k<8;k++) z += (a0r[k]*fr[k] + c0r[k]) * w1c[k];
    s += z; q += z*z;
  }
  ls[wv][lane]=s; lq[wv][lane]=q;
  __syncthreads();
  if(tid < 64){
    float S = ls[0][tid]+ls[1][tid]+ls[2][tid]+ls[3][tid];
    float Q = lq[0][tid]+lq[1][tid]+lq[2][tid]+lq[3][tid];
    atomicAdd(&sum1[tid], S);
    atomicAdd(&sq1[tid], Q);
  }
}

// ---------------- mstats2: z2 stats via MFMA (feats-fed, proven) ----------
__global__ __launch_bounds__(256,2) void k_mstats2(
    const float* __restrict__ feats,
    const float* __restrict__ a0, const float* __restrict__ c0,
    const float* __restrict__ a1, const float* __restrict__ c1,
    const float* __restrict__ W1, const u16* __restrict__ W2t,
    float* __restrict__ sum2, float* __restrict__ sq2){
  __shared__ u16 T1[256*72];
  int tid = threadIdx.x, lane = tid&63, wid = tid>>6, l15 = lane&15, lg = lane>>4;
  float s2[2] = {0.f,0.f}, q2[2] = {0.f,0.f};

  for(int cch=0; cch<4; cch++){
    int p = blockIdx.x*1024 + cch*256 + tid;
    const float4* fr = (const float4*)&feats[(size_t)p*8];
    float4 fa = fr[0], fb = fr[1];
    float f[8] = {fa.x,fa.y,fa.z,fa.w,fb.x,fb.y,fb.z,fb.w};
    float y0[8];
    #pragma unroll
    for(int k=0;k<8;k++) y0[k] = a0[k]*f[k] + c0[k];
    u32 pk[32];
    #pragma unroll
    for(int jj=0;jj<32;jj++){
      float s0=0.f, s1=0.f;
      #pragma unroll
      for(int k=0;k<8;k++){ s0 += y0[k]*W1[k*64+2*jj]; s1 += y0[k]*W1[k*64+2*jj+1]; }
      float v0f = fmaxf(a1[2*jj]*s0   + c1[2*jj],   0.f);
      float v1f = fmaxf(a1[2*jj+1]*s1 + c1[2*jj+1], 0.f);
      pk[jj] = (u32)f2bfh(v0f) | ((u32)f2bfh(v1f)<<16);
    }
    __syncthreads();
    {
      uint4* dst = (uint4*)&T1[tid*72];
      #pragma unroll
      for(int q=0;q<8;q++) dst[q] = make_uint4(pk[4*q],pk[4*q+1],pk[4*q+2],pk[4*q+3]);
    }
    __syncthreads();
    #pragma unroll
    for(int ci=0; ci<2; ci++){
      int ch = (wid + 4*ci)*16 + l15;
      const u16* wb = W2t + (size_t)ch*64 + lg*8;
      bf16x8 b0 = *(const bf16x8*)(wb);
      bf16x8 b1 = *(const bf16x8*)(wb + 32);
      for(int rt=0; rt<16; rt++){
        const u16* ap = T1 + (rt*16 + l15)*72 + lg*8;
        bf16x8 af0 = *(const bf16x8*)(ap);
        bf16x8 af1 = *(const bf16x8*)(ap + 32);
        f32x4 acc = {0.f,0.f,0.f,0.f};
        acc = __builtin_amdgcn_mfma_f32_16x16x32_bf16(af0, b0, acc, 0,0,0);
        acc = __builtin_amdgcn_mfma_f32_16x16x32_bf16(af1, b1, acc, 0,0,0);
        #pragma unroll
        for(int i=0;i<4;i++){ s2[ci] += acc[i]; q2[ci] += acc[i]*acc[i]; }
      }
    }
  }
  #pragma unroll
  for(int ci=0; ci<2; ci++){
    float s = s2[ci], q = q2[ci];
    s += __shfl_xor(s,16); s += __shfl_xor(s,32);
    q += __shfl_xor(q,16); q += __shfl_xor(q,32);
    if(lg == 0){
      int ch = (wid + 4*ci)*16 + l15;
      atomicAdd(&sum2[ch], s);
      atomicAdd(&sq2[ch], q);
    }
  }
}

// ---------------- chain2: 512-thread, feats-fed (proven r13) ------------
__global__ __launch_bounds__(512,1) void k_chain2(
    const float* __restrict__ feats, const u32* __restrict__ order,
    const float* __restrict__ a0, const float* __restrict__ c0,
    const float* __restrict__ a1, const float* __restrict__ c1,
    const float* __restrict__ a2, const float* __restrict__ c2,
    const float* __restrict__ W1, const u16* __restrict__ W2t,
    const u16* __restrict__ W3t,
    u32* __restrict__ y2s,
    float* __restrict__ sum3, float* __restrict__ sq3){
  __shared__ u16 T1[256*72];
  __shared__ u16 T2[256*136];
  int tid = threadIdx.x, lane = tid&63, wid = tid>>6, l15 = lane&15, lg = lane>>4;
  float s3[2] = {0.f,0.f}, q3[2] = {0.f,0.f};

  for(int cch=0; cch<4; cch++){
    u32 pk[32];
    if(tid < 256){
      int rr = blockIdx.x*1024 + cch*256 + tid;
      int p = (int)order[rr];
      const float4* fr = (const float4*)&feats[(size_t)p*8];
      float4 fa = fr[0], fb = fr[1];
      float f[8] = {fa.x,fa.y,fa.z,fa.w,fb.x,fb.y,fb.z,fb.w};
      float y0[8];
      #pragma unroll
      for(int k=0;k<8;k++) y0[k] = a0[k]*f[k] + c0[k];
      #pragma unroll
      for(int jj=0;jj<32;jj++){
        float s0=0.f, s1=0.f;
        #pragma unroll
        for(int k=0;k<8;k++){ s0 += y0[k]*W1[k*64+2*jj]; s1 += y0[k]*W1[k*64+2*jj+1]; }
        float v0f = fmaxf(a1[2*jj]*s0   + c1[2*jj],   0.f);
        float v1f = fmaxf(a1[2*jj+1]*s1 + c1[2*jj+1], 0.f);
        pk[jj] = (u32)f2bfh(v0f) | ((u32)f2bfh(v1f)<<16);
      }
    }
    __syncthreads();
    if(tid < 256){
      uint4* dst = (uint4*)&T1[tid*72];
      #pragma unroll
      for(int q=0;q<8;q++) dst[q] = make_uint4(pk[4*q],pk[4*q+1],pk[4*q+2],pk[4*q+3]);
    }
    __syncthreads();
    // L2: T1(256x64) @ W2t -> bn2relu -> T2(256x128); 1 ch-tile per wave
    {
      int ch = wid*16 + l15;
      const u16* wb = W2t + (size_t)ch*64 + lg*8;
      bf16x8 b0 = *(const bf16x8*)(wb);
      bf16x8 b1 = *(const bf16x8*)(wb + 32);
      float a2v = a2[ch], c2v = c2[ch];
      for(int rt=0; rt<16; rt++){
        const u16* ap = T1 + (rt*16 + l15)*72 + lg*8;
        bf16x8 af0 = *(const bf16x8*)(ap);
        bf16x8 af1 = *(const bf16x8*)(ap + 32);
        f32x4 acc = {0.f,0.f,0.f,0.f};
        acc = __builtin_amdgcn_mfma_f32_16x16x32_bf16(af0, b0, acc, 0,0,0);
        acc = __builtin_amdgcn_mfma_f32_16x16x32_bf16(af1, b1, acc, 0,0,0);
        int rbase = rt*16 + lg*4;
        #pragma unroll
        for(int i=0;i<4;i++)
          T2[(rbase+i)*136 + ch] = f2bfh(fmaxf(a2v*acc[i] + c2v, 0.f));
      }
    }
    __syncthreads();
    {
      const u32* T2w = (const u32*)T2;
      u32 base = (u32)blockIdx.x*1024u + (u32)cch*256u;
      for(int i=tid; i<256*64; i+=512){
        int row = i>>6, w = i&63;
        y2s[(size_t)(base+row)*64 + w] = T2w[row*68 + w];
      }
    }
    // L3: z3 = T2(256x128) @ W3t; 2 ch-tiles per wave; stats only
    #pragma unroll
    for(int ci=0; ci<2; ci++){
      int ch = (wid + 8*ci)*16 + l15;
      const u16* wb = W3t + (size_t)ch*128 + lg*8;
      bf16x8 b[4];
      #pragma unroll
      for(int ks=0; ks<4; ks++) b[ks] = *(const bf16x8*)(wb + ks*32);
      for(int rt=0; rt<16; rt++){
        const u16* ap = T2 + (rt*16 + l15)*136 + lg*8;
        f32x4 acc = {0.f,0.f,0.f,0.f};
        #pragma unroll
        for(int ks=0; ks<4; ks++){
          bf16x8 af = *(const bf16x8*)(ap + ks*32);
          acc = __builtin_amdgcn_mfma_f32_16x16x32_bf16(af, b[ks], acc, 0,0,0);
        }
        #pragma unroll
        for(int i=0;i<4;i++){ s3[ci] += acc[i]; q3[ci] += acc[i]*acc[i]; }
      }
    }
  }
  #pragma unroll
  for(int ci=0; ci<2; ci++){
    float s = s3[ci], q = q3[ci];
    s += __shfl_xor(s,16); s += __shfl_xor(s,32);
    q += __shfl_xor(q,16); q += __shfl_xor(q,32);
    if(lg == 0){
      int ch = (wid + 8*ci)*16 + l15;
      atomicAdd(&sum3[ch], s);
      atomicAdd(&sq3[ch], q);
    }
  }
}

// ---------------- mega7: mega6 + f2bfh + paired-channel segmax ----------
__global__ __launch_bounds__(512,4) void k_mega7(
    const u32* __restrict__ offsets, const u32* __restrict__ y2s,
    const float* __restrict__ a3, const float* __restrict__ c3,
    const u16* __restrict__ W3t, const u16* __restrict__ W4t,
    const u16* __restrict__ Wct,
    const float* __restrict__ b4, const float* __restrict__ bc,
    u16* __restrict__ comp){
  __shared__ __align__(16) char SM[78208];
  u16* T3  = (u16*)(SM);            // [80][264] 42240
  u16* T2s = (u16*)(SM + 42240);    // [80][136] 21760 (staging; dead after L3)
  u16* Tz0 = (u16*)(SM + 42240);    // [80][72] 11520
  u16* Tz1 = (u16*)(SM + 53760);    // [80][72] 11520
  u16* TA  = (u16*)(SM + 65280);    // [80][72] 11520
  u32* vst = (u32*)(SM + 76800);    // [VCAP+1]
  float* bb = (float*)(SM + 77152); // [256] b4 preload
  u32* hdr = (u32*)(SM + 78176);    // [4]

  int tid = threadIdx.x, lane = tid & 63, wid = tid >> 6;
  int l15 = lane & 15, lg = lane >> 4;
  int cg = wid & 3, rh = wid >> 2;
  int nvt = rh ? 2 : 3, vt0 = rh ? 3 : 0;

  if(tid == 0){
    u32 t0 = (u32)blockIdx.x * 64u;
    u32 lo=0, hi=SS;
    while(lo<hi){ u32 mid=(lo+hi)>>1; if(offsets[mid] < t0) lo=mid+1; else hi=mid; }
    u32 vlo = lo, vhi;
    if(blockIdx.x == NB-1) vhi = SS;
    else {
      u32 t1 = t0 + 64u;
      lo = vlo; hi = SS;
      while(lo<hi){ u32 mid=(lo+hi)>>1; if(offsets[mid] < t1) lo=mid+1; else hi=mid; }
      vhi = lo;
    }
    hdr[0]=vlo; hdr[1]=vhi; hdr[2]=offsets[vlo]; hdr[3]=offsets[vhi];
  }
  if(tid < 256) bb[tid] = b4[tid];
  __syncthreads();
  u32 vlo=hdr[0], vhi=hdr[1], start=hdr[2], end=hdr[3];
  int R = (int)(end - start); if(R > RCAP) R = RCAP;
  int V = (int)(vhi - vlo);   if(V > VCAP) V = VCAP;

  if(tid <= VCAP){
    u32 o = (tid <= V) ? offsets[vlo + tid] : end;
    int s = (int)(o - start); if(s > RCAP) s = RCAP;
    vst[tid] = (u32)s;
  }

  {
    u32* T2w = (u32*)T2s;
    for(int i=tid; i<RCAP*64; i+=512){
      int row = i>>6, w = i&63;
      u32 val = (row < R) ? y2s[(size_t)(start+row)*64 + w] : 0u;
      T2w[row*68 + w] = val;
    }
  }
  __syncthreads();

  for(int ci=0; ci<2; ci++){
    int ch = (wid + 8*ci)*16 + l15;
    const u16* wb = W3t + (size_t)ch*128 + lg*8;
    bf16x8 b[4];
    #pragma unroll
    for(int ks=0; ks<4; ks++) b[ks] = *(const bf16x8*)(wb + ks*32);
    float a3v = a3[ch], c3v = c3[ch];
    for(int rt=0; rt<5; rt++){
      const u16* ap = T2s + (rt*16 + l15)*136 + lg*8;
      f32x4 acc = {0.f,0.f,0.f,0.f};
      #pragma unroll
      for(int ks=0; ks<4; ks++){
        bf16x8 af = *(const bf16x8*)(ap + ks*32);
        acc = __builtin_amdgcn_mfma_f32_16x16x32_bf16(af, b[ks], acc, 0,0,0);
      }
      int rbase = rt*16 + lg*4;
      #pragma unroll
      for(int i=0;i<4;i++)
        T3[(rbase+i)*264 + ch] = f2bfh(fmaxf(a3v*acc[i] + c3v, 0.f));
    }
  }
  __syncthreads();

  f32x4 acc3[3];
  #pragma unroll
  for(int i=0;i<3;i++) acc3[i] = (f32x4){0.f,0.f,0.f,0.f};
  int ch4 = cg*16 + l15;

  for(int pr=0; pr<2; pr++){
    int oc0 = 2*pr, oc1 = 2*pr + 1;
    {
      const u16* wb0 = W4t + (size_t)(oc0*64 + ch4)*256 + lg*8;
      const u16* wb1 = W4t + (size_t)(oc1*64 + ch4)*256 + lg*8;
      bf16x8 b0[8], b1[8];
      #pragma unroll
      for(int ks=0; ks<8; ks++){
        b0[ks] = *(const bf16x8*)(wb0 + ks*32);
        b1[ks] = *(const bf16x8*)(wb1 + ks*32);
      }
      int rtB = rh ? 3 : 0, rtE = rh ? 5 : 3;
      for(int rt=rtB; rt<rtE; rt++){
        const u16* ap = T3 + (rt*16 + l15)*264 + lg*8;
        f32x4 aA = {0.f,0.f,0.f,0.f}, aB = {0.f,0.f,0.f,0.f};
        #pragma unroll
        for(int ks=0; ks<8; ks++){
          bf16x8 af = *(const bf16x8*)(ap + ks*32);
          aA = __builtin_amdgcn_mfma_f32_16x16x32_bf16(af, b0[ks], aA, 0,0,0);
          aB = __builtin_amdgcn_mfma_f32_16x16x32_bf16(af, b1[ks], aB, 0,0,0);
        }
        int rbase = rt*16 + lg*4;
        #pragma unroll
        for(int i=0;i<4;i++){
          Tz0[(rbase+i)*72 + ch4] = f2bfh(aA[i]);
          Tz1[(rbase+i)*72 + ch4] = f2bfh(aB[i]);
        }
      }
    }
    __syncthreads();
    // segmax oc0 (paired channels): Tz0 -> TA
    {
      const u32* Tzw = (const u32*)Tz0;
      u32* TAw = (u32*)TA;
      for(int i=tid; i<VCAP*32; i+=512){
        int v = i>>5, k2 = i&31;
        u32 r0 = vst[v], r1 = vst[v+1];
        u32 outw = 0;
        if(r1 > r0){
          float m0 = -3.0e38f, m1 = -3.0e38f;
          for(u32 r=r0; r<r1; r++){
            u32 w = Tzw[r*36 + k2];
            m0 = fmaxf(m0, bf2f((u16)w));
            m1 = fmaxf(m1, bf2f((u16)(w>>16)));
          }
          u16 o0 = f2bfh(m0 + bb[oc0*64 + 2*k2]);
          u16 o1 = f2bfh(m1 + bb[oc0*64 + 2*k2+1]);
          outw = (u32)o0 | ((u32)o1<<16);
        }
        TAw[v*36 + k2] = outw;
      }
    }
    __syncthreads();
    {
      const u16* wb = Wct + (size_t)ch4*256 + oc0*64 + lg*8;
      bf16x8 c0f = *(const bf16x8*)(wb);
      bf16x8 c1f = *(const bf16x8*)(wb + 32);
      #pragma unroll
      for(int s=0; s<3; s++){
        if(s < nvt){
          int vt = vt0 + s;
          const u16* ap = TA + (vt*16 + l15)*72 + lg*8;
          bf16x8 af0 = *(const bf16x8*)(ap);
          bf16x8 af1 = *(const bf16x8*)(ap + 32);
          acc3[s] = __builtin_amdgcn_mfma_f32_16x16x32_bf16(af0, c0f, acc3[s], 0,0,0);
          acc3[s] = __builtin_amdgcn_mfma_f32_16x16x32_bf16(af1, c1f, acc3[s], 0,0,0);
        }
      }
    }
    __syncthreads();
    // segmax oc1 (paired channels): Tz1 -> TA
    {
      const u32* Tzw = (const u32*)Tz1;
      u32* TAw = (u32*)TA;
      for(int i=tid; i<VCAP*32; i+=512){
        int v = i>>5, k2 = i&31;
        u32 r0 = vst[v], r1 = vst[v+1];
        u32 outw = 0;
        if(r1 > r0){
          float m0 = -3.0e38f, m1 = -3.0e38f;
          for(u32 r=r0; r<r1; r++){
            u32 w = Tzw[r*36 + k2];
            m0 = fmaxf(m0, bf2f((u16)w));
            m1 = fmaxf(m1, bf2f((u16)(w>>16)));
          }
          u16 o0 = f2bfh(m0 + bb[oc1*64 + 2*k2]);
          u16 o1 = f2bfh(m1 + bb[oc1*64 + 2*k2+1]);
          outw = (u32)o0 | ((u32)o1<<16);
        }
        TAw[v*36 + k2] = outw;
      }
    }
    __syncthreads();
    {
      const u16* wb = Wct + (size_t)ch4*256 + oc1*64 + lg*8;
      bf16x8 c0f = *(const bf16x8*)(wb);
      bf16x8 c1f = *(const bf16x8*)(wb + 32);
      #pragma unroll
      for(int s=0; s<3; s++){
        if(s < nvt){
          int vt = vt0 + s;
          const u16* ap = TA + (vt*16 + l15)*72 + lg*8;
          bf16x8 af0 = *(const bf16x8*)(ap);
          bf16x8 af1 = *(const bf16x8*)(ap + 32);
          acc3[s] = __builtin_amdgcn_mfma_f32_16x16x32_bf16(af0, c0f, acc3[s], 0,0,0);
          acc3[s] = __builtin_amdgcn_mfma_f32_16x16x32_bf16(af1, c1f, acc3[s], 0,0,0);
        }
      }
    }
    __syncthreads();
  }

  {
    float bcv = bc[ch4];
    #pragma unroll
    for(int s=0; s<3; s++){
      if(s < nvt){
        int vt = vt0 + s;
        int vbase = vt*16 + lg*4;
        #pragma unroll
        for(int i=0;i<4;i++){
          int vox = vbase + i;
          if(vox < V){
            bool nz = vst[vox+1] > vst[vox];
            float val = nz ? fmaxf(acc3[s][i] + bcv, 0.f) : 0.f;
            comp[(size_t)(vlo+vox)*64 + ch4] = f2bfh(val);
          }
        }
      }
    }
  }
}

// ---------------- residual image from comp (proven) ----------------
__global__ __launch_bounds__(256) void k_resid(const u16* __restrict__ comp,
                                               float* __restrict__ out){
  __shared__ u32 cl[4*128*32];
  int t = threadIdx.x;
  int blk = blockIdx.x;
  int wq = blk & 3, h = (blk>>2) & 63, b = blk>>8;
  int w0 = wq*128;
  for(int fr=0; fr<4; fr++){
    const u32* src = (const u32*)comp + ((size_t)(((b*4+fr)*64 + h)*512 + w0))*32;
    for(int i=t; i<4096; i+=256){
      int vox = i>>5, wd = i&31;
      cl[fr*4096 + vox*32 + (wd ^ (vox&31))] = src[i];
    }
  }
  __syncthreads();
  int wl = t & 127, half = t >> 7;
  int mv = wl & 31;
  for(int ch = half; ch < 64; ch += 2){
    u32 wr3 = cl[3*4096 + wl*32 + ((ch>>1) ^ mv)];
    float r3 = bf2f((ch&1) ? (u16)(wr3>>16) : (u16)(wr3&0xFFFFu));
    #pragma unroll
    for(int fr=0; fr<3; fr++){
      u32 wrf = cl[fr*4096 + wl*32 + ((ch>>1) ^ mv)];
      float vf = bf2f((ch&1) ? (u16)(wrf>>16) : (u16)(wrf&0xFFFFu));
      out[(((size_t)(b*192 + fr*64 + ch))*64 + h)*512 + w0 + wl] = r3 - vf;
    }
  }
}

// ------------------------------- launcher -------------------------------------
extern "C" void kernel_launch(void* const* d_in, const int* in_sizes, int n_in,
                              void* d_out, int out_size, void* d_ws, size_t ws_size,
                              hipStream_t stream){
  const float* pts  = (const float*)d_in[0];
  const int*  coors = (const int*)d_in[1];
  const float* g0 = (const float*)d_in[2];
  const float* b0 = (const float*)d_in[3];
  const float* W1 = (const float*)d_in[4];
  const float* g1 = (const float*)d_in[5];
  const float* b1 = (const float*)d_in[6];
  const float* W2 = (const float*)d_in[7];
  const float* g2 = (const float*)d_in[8];
  const float* b2 = (const float*)d_in[9];
  const float* W3 = (const float*)d_in[10];
  const float* g3 = (const float*)d_in[11];
  const float* b3 = (const float*)d_in[12];
  const float* W4 = (const float*)d_in[13];
  const float* b4 = (const float*)d_in[14];
  const float* Wc = (const float*)d_in[15];
  const float* bc = (const float*)d_in[16];
  float* out = (float*)d_out;
  (void)in_sizes; (void)n_in; (void)out_size; (void)ws_size;

  char* ws = (char*)d_ws;
  size_t off = 0;
  auto alloc = [&](size_t bytes)->void*{
    void* p = ws + off;
    off += (bytes + 255) & ~(size_t)255;
    return p;
  };
  u32*  counts  = (u32*)alloc((size_t)SS*4);
  float* vsum   = (float*)alloc((size_t)SS*3*4);
  float* stats  = (float*)alloc(8192);
  size_t zero_bytes = off;
  u32*  lin     = (u32*)alloc((size_t)NPTS*4);
  u32*  offsets = (u32*)alloc((size_t)(SS+1)*4);
  u32*  cursor  = (u32*)alloc((size_t)SS*4);
  u32*  order   = (u32*)alloc((size_t)NPTS*4);
  u32*  blockSums = (u32*)alloc(1024);
  u16*  comp    = (u16*)alloc((size_t)SS*64*2);
  u16*  W2t = (u16*)alloc(8192*2);
  u16*  W3t = (u16*)alloc(32768*2);
  u16*  W4t = (u16*)alloc(65536*2);
  u16*  Wct = (u16*)alloc(16384*2);
  float* feats = (float*)alloc((size_t)NPTS*8*4);   // 16 MB
  u32*  y2s = (u32*)alloc((size_t)NPTS*64*4);       // 134 MB

  float* sum0=stats+0,   *sq0=stats+8,    *a0=stats+16,   *c0=stats+24;
  float* sum1=stats+32,  *sq1=stats+96,   *a1=stats+160,  *c1=stats+224;
  float* sum2=stats+288, *sq2=stats+416,  *a2=stats+544,  *c2=stats+672;
  float* sum3=stats+800, *sq3=stats+1056, *a3=stats+1312, *c3=stats+1568;

  hipMemsetAsync(d_ws, 0, zero_bytes, stream);

  k_prep   <<<480, 256,0,stream>>>(W2, W3, W4, Wc, W2t, W3t, W4t, Wct);
  k_lin    <<<2048,256,0,stream>>>(pts, coors, lin, counts, vsum);
  k_scan_a <<<256, 256,0,stream>>>(counts, blockSums);
  k_scan_b <<<1,   64, 0,stream>>>(blockSums);
  k_scan_c <<<256, 256,0,stream>>>(counts, blockSums, offsets, cursor);
  k_scatter<<<2048,256,0,stream>>>(lin, cursor, order);

  k_stats0 <<<2048,256,0,stream>>>(pts, lin, counts, vsum, feats, sum0, sq0);
  k_fold   <<<1,   64, 0,stream>>>(sum0, sq0, g0, b0, a0, c0, 8);
  k_stats1b<<<512, 256,0,stream>>>(feats, a0, c0, W1, sum1, sq1);
  k_fold   <<<1,   64, 0,stream>>>(sum1, sq1, g1, b1, a1, c1, 64);
  k_mstats2<<<512, 256,0,stream>>>(feats, a0,c0,a1,c1, W1, W2t, sum2, sq2);
  k_fold   <<<2,   64, 0,stream>>>(sum2, sq2, g2, b2, a2, c2, 128);
  k_chain2 <<<512, 512,0,stream>>>(feats, order, a0,c0,a1,c1,a2,c2, W1, W2t, W3t,
                                   y2s, sum3, sq3);
  k_fold   <<<4,   64, 0,stream>>>(sum3, sq3, g3, b3, a3, c3, 256);

  k_mega7  <<<NB,  512,0,stream>>>(offsets, y2s, a3,c3, W3t, W4t, Wct, b4, bc, comp);
  k_resid  <<<512, 256,0,stream>>>(comp, out);
}